// Round 1
// baseline (553.615 us; speedup 1.0000x reference)
//
#include <hip/hip_runtime.h>
#include <math.h>

#define DIM 192
#define NHD 6
#define HD 32
#define KSZ 7
#define HID 768
#define IMH 128
#define IMW 128
#define NPIX (IMH*IMW)

// ---------------- LayerNorm: one wave (64 lanes) per pixel, C=192=3*64 ----------------
__global__ __launch_bounds__(256) void ln_kernel(const float* __restrict__ x,
                                                 const float* __restrict__ w,
                                                 const float* __restrict__ b,
                                                 float* __restrict__ out)
{
    int wid  = (blockIdx.x * 256 + threadIdx.x) >> 6;
    int lane = threadIdx.x & 63;
    if (wid >= NPIX) return;
    const float* xp = x + (size_t)wid * DIM;
    float v0 = xp[lane], v1 = xp[lane + 64], v2 = xp[lane + 128];
    float s = v0 + v1 + v2;
    #pragma unroll
    for (int off = 32; off > 0; off >>= 1) s += __shfl_down(s, off);
    float mu = __shfl(s, 0) * (1.0f / DIM);
    float d0 = v0 - mu, d1 = v1 - mu, d2 = v2 - mu;
    float q = d0*d0 + d1*d1 + d2*d2;
    #pragma unroll
    for (int off = 32; off > 0; off >>= 1) q += __shfl_down(q, off);
    float rstd = rsqrtf(__shfl(q, 0) * (1.0f / DIM) + 1e-5f);
    float* op = out + (size_t)wid * DIM;
    op[lane]       = d0 * rstd * w[lane]       + b[lane];
    op[lane + 64]  = d1 * rstd * w[lane + 64]  + b[lane + 64];
    op[lane + 128] = d2 * rstd * w[lane + 128] + b[lane + 128];
}

// ---------------- Tiled fp32 GEMM: C[M,N] = A[M,K] @ W[N,K]^T + epilogue ----------------
// mode 0: +bias      mode 1: gelu(+bias)      mode 2: resid + |gamma[q-1]|*(+bias)
#define TM 64
#define TN 64
#define TK 16
__global__ __launch_bounds__(256) void gemm_kernel(
    const float* __restrict__ A, const float* __restrict__ Wt,
    const float* __restrict__ bias, float* __restrict__ C,
    const float* __restrict__ resid, const float* __restrict__ gamma,
    const int* __restrict__ quality,
    int M, int N, int K, int mode)
{
    __shared__ float As[TK][TM + 4];   // +4: rows are 272B -> float4-aligned
    __shared__ float Bs[TK][TN + 4];
    int m0 = blockIdx.x * TM;
    int n0 = blockIdx.y * TN;
    int tid = threadIdx.x;
    int tx = tid & 15, ty = tid >> 4;   // 16x16 thread grid, 4x4 microtile each
    int lr = tid >> 2;                  // load row within tile (0..63)
    int lk = (tid & 3) * 4;             // load k-group (0,4,8,12)

    float acc[4][4] = {};
    for (int k0 = 0; k0 < K; k0 += TK) {
        float4 av = *(const float4*)&A [(size_t)(m0 + lr) * K + k0 + lk];
        float4 bv = *(const float4*)&Wt[(size_t)(n0 + lr) * K + k0 + lk];
        As[lk+0][lr] = av.x; As[lk+1][lr] = av.y; As[lk+2][lr] = av.z; As[lk+3][lr] = av.w;
        Bs[lk+0][lr] = bv.x; Bs[lk+1][lr] = bv.y; Bs[lk+2][lr] = bv.z; Bs[lk+3][lr] = bv.w;
        __syncthreads();
        #pragma unroll
        for (int k = 0; k < TK; k++) {
            float4 a = *(const float4*)&As[k][ty * 4];
            float4 b = *(const float4*)&Bs[k][tx * 4];
            float ar[4] = {a.x, a.y, a.z, a.w};
            float br[4] = {b.x, b.y, b.z, b.w};
            #pragma unroll
            for (int i = 0; i < 4; i++)
                #pragma unroll
                for (int j = 0; j < 4; j++)
                    acc[i][j] += ar[i] * br[j];
        }
        __syncthreads();
    }

    int s = quality ? (quality[0] - 1) : 0;
    #pragma unroll
    for (int i = 0; i < 4; i++) {
        int m = m0 + ty * 4 + i;
        #pragma unroll
        for (int j = 0; j < 4; j++) {
            int n = n0 + tx * 4 + j;
            float v = acc[i][j] + bias[n];
            if (mode == 1) {
                v = 0.5f * v * (1.0f + erff(v * 0.70710678118654752f));
            } else if (mode == 2) {
                float g = fabsf(gamma[s * DIM + n]);
                v = resid[(size_t)m * N + n] + g * v;
            }
            C[(size_t)m * N + n] = v;
        }
    }
}

// ---------------- Neighborhood attention: one thread per (pixel, head) ----------------
// qkv layout per pixel: [3][6][32]  (q at 0, k at +192, v at +384)
__global__ __launch_bounds__(256) void attn_kernel(
    const float* __restrict__ qkv, const float* __restrict__ rpb,
    float* __restrict__ out)
{
    int t = blockIdx.x * 256 + threadIdx.x;
    if (t >= NPIX * NHD) return;
    int head = t % NHD;
    int pix  = t / NHD;
    int i = pix >> 7, j = pix & (IMW - 1);
    const float scale = 0.17677669529663687f;  // 32^-0.5

    const float* qp = qkv + (size_t)pix * 576 + head * HD;
    float q[HD];
    #pragma unroll
    for (int d = 0; d < HD; d++) q[d] = qp[d] * scale;

    int si = i - 3; si = si < 0 ? 0 : (si > IMH - KSZ ? IMH - KSZ : si);
    int sj = j - 3; sj = sj < 0 ? 0 : (sj > IMW - KSZ ? IMW - KSZ : sj);

    float mx = -1e30f, l = 0.f;
    float acc[HD] = {};
    for (int ki = 0; ki < KSZ; ki++) {
        int ii = si + ki;
        int reli = ii - i + 6;
        const float* rb = rpb + (head * 13 + reli) * 13 + (sj - j + 6);
        for (int kj = 0; kj < KSZ; kj++) {
            int jj = sj + kj;
            const float* kp = qkv + (size_t)(ii * IMW + jj) * 576 + 192 + head * HD;
            float sc = 0.f;
            #pragma unroll
            for (int d = 0; d < HD; d++) sc += q[d] * kp[d];
            sc += rb[kj];
            float mn = fmaxf(mx, sc);
            float co = __expf(mx - mn);
            float p  = __expf(sc - mn);
            l = l * co + p;
            const float* vp = kp + 192;
            #pragma unroll
            for (int d = 0; d < HD; d++) acc[d] = acc[d] * co + p * vp[d];
            mx = mn;
        }
    }
    float rl = 1.f / l;
    float* op = out + (size_t)pix * DIM + head * HD;
    #pragma unroll
    for (int d = 0; d < HD; d++) op[d] = acc[d] * rl;
}

extern "C" void kernel_launch(void* const* d_in, const int* in_sizes, int n_in,
                              void* d_out, int out_size, void* d_ws, size_t ws_size,
                              hipStream_t stream)
{
    const float* x      = (const float*)d_in[0];
    const float* qkv_w  = (const float*)d_in[1];
    const float* qkv_b  = (const float*)d_in[2];
    const float* proj_w = (const float*)d_in[3];
    const float* proj_b = (const float*)d_in[4];
    const float* rpb    = (const float*)d_in[5];
    const float* ln1_w  = (const float*)d_in[6];
    const float* ln1_b  = (const float*)d_in[7];
    const float* ln2_w  = (const float*)d_in[8];
    const float* ln2_b  = (const float*)d_in[9];
    const float* fc1_w  = (const float*)d_in[10];
    const float* fc1_b  = (const float*)d_in[11];
    const float* fc2_w  = (const float*)d_in[12];
    const float* fc2_b  = (const float*)d_in[13];
    const float* gamma1 = (const float*)d_in[14];
    const float* gamma2 = (const float*)d_in[15];
    const int*   quality= (const int*)d_in[16];
    float* out = (float*)d_out;

    // workspace: h(12.6MB) | attn_out(12.6MB) | qkv-or-m1(50.3MB)  => 75.5MB total
    float* h        = (float*)d_ws;                       // NPIX*DIM, reused for h2
    float* attn_out = h + (size_t)NPIX * DIM;             // NPIX*DIM
    float* qkvbuf   = attn_out + (size_t)NPIX * DIM;      // NPIX*576, reused as m1 (NPIX*768)

    // 1. LN1: x -> h
    ln_kernel<<<NPIX / 4, 256, 0, stream>>>(x, ln1_w, ln1_b, h);
    // 2. QKV GEMM: h @ qkv_w^T + qkv_b -> qkvbuf   (M=16384, N=576, K=192)
    gemm_kernel<<<dim3(NPIX / TM, 576 / TN), 256, 0, stream>>>(
        h, qkv_w, qkv_b, qkvbuf, nullptr, nullptr, nullptr, NPIX, 576, DIM, 0);
    // 3. neighborhood attention -> attn_out
    attn_kernel<<<NPIX * NHD / 256, 256, 0, stream>>>(qkvbuf, rpb, attn_out);
    // 4. proj + residual: out = x + |g1|*(attn_out @ proj_w^T + proj_b)
    gemm_kernel<<<dim3(NPIX / TM, DIM / TN), 256, 0, stream>>>(
        attn_out, proj_w, proj_b, out, x, gamma1, quality, NPIX, DIM, DIM, 2);
    // 5. LN2: out -> h
    ln_kernel<<<NPIX / 4, 256, 0, stream>>>(out, ln2_w, ln2_b, h);
    // 6. FC1 + GELU: gelu(h @ fc1_w^T + fc1_b) -> m1   (N=768)
    gemm_kernel<<<dim3(NPIX / TM, HID / TN), 256, 0, stream>>>(
        h, fc1_w, fc1_b, qkvbuf, nullptr, nullptr, nullptr, NPIX, HID, DIM, 1);
    // 7. FC2 + residual: out = out + |g2|*(m1 @ fc2_w^T + fc2_b)   (K=768)
    gemm_kernel<<<dim3(NPIX / TM, DIM / TN), 256, 0, stream>>>(
        qkvbuf, fc2_w, fc2_b, out, out, gamma2, quality, NPIX, DIM, HID, 2);
}

// Round 2
// 362.466 us; speedup vs baseline: 1.5274x; 1.5274x over previous
//
#include <hip/hip_runtime.h>
#include <math.h>

#define DIM 192
#define NHD 6
#define HD 32
#define KSZ 7
#define HID 768
#define IMH 128
#define IMW 128
#define NPIX (IMH*IMW)
#define WIN 14

// ---------------- LayerNorm: one wave (64 lanes) per pixel, C=192=3*64 ----------------
__global__ __launch_bounds__(256) void ln_kernel(const float* __restrict__ x,
                                                 const float* __restrict__ w,
                                                 const float* __restrict__ b,
                                                 float* __restrict__ out)
{
    int wid  = (blockIdx.x * 256 + threadIdx.x) >> 6;
    int lane = threadIdx.x & 63;
    if (wid >= NPIX) return;
    const float* xp = x + (size_t)wid * DIM;
    float v0 = xp[lane], v1 = xp[lane + 64], v2 = xp[lane + 128];
    float s = v0 + v1 + v2;
    #pragma unroll
    for (int off = 32; off > 0; off >>= 1) s += __shfl_down(s, off);
    float mu = __shfl(s, 0) * (1.0f / DIM);
    float d0 = v0 - mu, d1 = v1 - mu, d2 = v2 - mu;
    float q = d0*d0 + d1*d1 + d2*d2;
    #pragma unroll
    for (int off = 32; off > 0; off >>= 1) q += __shfl_down(q, off);
    float rstd = rsqrtf(__shfl(q, 0) * (1.0f / DIM) + 1e-5f);
    float* op = out + (size_t)wid * DIM;
    op[lane]       = d0 * rstd * w[lane]       + b[lane];
    op[lane + 64]  = d1 * rstd * w[lane + 64]  + b[lane + 64];
    op[lane + 128] = d2 * rstd * w[lane + 128] + b[lane + 128];
}

// ---------------- Tiled fp32 GEMM: C[M,N] = A[M,K] @ W[N,K]^T + epilogue ----------------
// mode 0: +bias      mode 1: gelu(+bias)      mode 2: resid + |gamma[q-1]|*(+bias)
#define TM 64
#define TN 64
#define TK 16
__global__ __launch_bounds__(256) void gemm_kernel(
    const float* __restrict__ A, const float* __restrict__ Wt,
    const float* __restrict__ bias, float* __restrict__ C,
    const float* __restrict__ resid, const float* __restrict__ gamma,
    const int* __restrict__ quality,
    int M, int N, int K, int mode)
{
    __shared__ float As[TK][TM + 4];
    __shared__ float Bs[TK][TN + 4];
    int m0 = blockIdx.x * TM;
    int n0 = blockIdx.y * TN;
    int tid = threadIdx.x;
    int tx = tid & 15, ty = tid >> 4;
    int lr = tid >> 2;
    int lk = (tid & 3) * 4;

    float acc[4][4] = {};
    for (int k0 = 0; k0 < K; k0 += TK) {
        float4 av = *(const float4*)&A [(size_t)(m0 + lr) * K + k0 + lk];
        float4 bv = *(const float4*)&Wt[(size_t)(n0 + lr) * K + k0 + lk];
        As[lk+0][lr] = av.x; As[lk+1][lr] = av.y; As[lk+2][lr] = av.z; As[lk+3][lr] = av.w;
        Bs[lk+0][lr] = bv.x; Bs[lk+1][lr] = bv.y; Bs[lk+2][lr] = bv.z; Bs[lk+3][lr] = bv.w;
        __syncthreads();
        #pragma unroll
        for (int k = 0; k < TK; k++) {
            float4 a = *(const float4*)&As[k][ty * 4];
            float4 b = *(const float4*)&Bs[k][tx * 4];
            float ar[4] = {a.x, a.y, a.z, a.w};
            float br[4] = {b.x, b.y, b.z, b.w};
            #pragma unroll
            for (int i = 0; i < 4; i++)
                #pragma unroll
                for (int j = 0; j < 4; j++)
                    acc[i][j] += ar[i] * br[j];
        }
        __syncthreads();
    }

    int s = quality ? (quality[0] - 1) : 0;
    #pragma unroll
    for (int i = 0; i < 4; i++) {
        int m = m0 + ty * 4 + i;
        #pragma unroll
        for (int j = 0; j < 4; j++) {
            int n = n0 + tx * 4 + j;
            float v = acc[i][j] + bias[n];
            if (mode == 1) {
                v = 0.5f * v * (1.0f + erff(v * 0.70710678118654752f));
            } else if (mode == 2) {
                float g = fabsf(gamma[s * DIM + n]);
                v = resid[(size_t)m * N + n] + g * v;
            }
            C[(size_t)m * N + n] = v;
        }
    }
}

// ---------------- Neighborhood attention v2: block per (8x8 tile, head) ----------------
// LDS-staged 14x14 K/V window; thread = (pixel, dim-quarter); online softmax.
__global__ __launch_bounds__(256) void attn_kernel2(
    const float* __restrict__ qkv, const float* __restrict__ rpb,
    float* __restrict__ out)
{
    __shared__ float Ks[WIN*WIN][36];   // stride 36 floats: 16B-aligned rows, bank-spread
    __shared__ float Vs[WIN*WIN][36];
    __shared__ float rpbs[13 * 13];

    int head = blockIdx.y;
    int tile = blockIdx.x;            // 0..255
    int ti0 = (tile >> 4) * 8;
    int tj0 = (tile & 15) * 8;
    int wi0 = ti0 - 3; wi0 = wi0 < 0 ? 0 : (wi0 > IMH - WIN ? IMH - WIN : wi0);
    int wj0 = tj0 - 3; wj0 = wj0 < 0 ? 0 : (wj0 > IMW - WIN ? IMW - WIN : wj0);

    int tid = threadIdx.x;

    // Stage K/V window: 196 rows x 32 floats, 8 threads per row (float4 each)
    {
        int part = tid & 7;
        for (int r = tid >> 3; r < WIN * WIN; r += 32) {
            int gi = wi0 + r / WIN, gj = wj0 + r % WIN;
            const float* src = qkv + (size_t)(gi * IMW + gj) * 576 + DIM + head * HD + part * 4;
            float4 kv = *(const float4*)src;
            float4 vv = *(const float4*)(src + DIM);
            *(float4*)&Ks[r][part * 4] = kv;
            *(float4*)&Vs[r][part * 4] = vv;
        }
    }
    if (tid < 169) rpbs[tid] = rpb[head * 169 + tid];

    // Per-thread setup while loads are in flight
    int p   = tid >> 2;               // local pixel 0..63
    int sub = tid & 3;                // dim quarter (8 dims)
    int pi = ti0 + (p >> 3), pj = tj0 + (p & 7);
    int si = pi - 3; si = si < 0 ? 0 : (si > IMH - KSZ ? IMH - KSZ : si);
    int sj = pj - 3; sj = sj < 0 ? 0 : (sj > IMW - KSZ ? IMW - KSZ : sj);
    int bi = si - wi0, bj = sj - wj0;

    const float scale = 0.17677669529663687f;   // 32^-0.5
    const float* qp = qkv + (size_t)(pi * IMW + pj) * 576 + head * HD + sub * 8;
    float4 q0 = *(const float4*)qp;
    float4 q1 = *(const float4*)(qp + 4);
    float q[8] = {q0.x*scale, q0.y*scale, q0.z*scale, q0.w*scale,
                  q1.x*scale, q1.y*scale, q1.z*scale, q1.w*scale};

    __syncthreads();

    float m = -1e30f, l = 0.f;
    float acc[8] = {};
    #pragma unroll
    for (int ki = 0; ki < KSZ; ki++) {
        int rbase = (bi + ki) * WIN + bj;
        const float* rb = &rpbs[(si + ki - pi + 6) * 13 + (sj - pj + 6)];
        #pragma unroll
        for (int kj = 0; kj < KSZ; kj++) {
            int n = rbase + kj;
            const float4* kr = (const float4*)&Ks[n][sub * 8];
            float4 ka = kr[0], kb = kr[1];
            float d = q[0]*ka.x + q[1]*ka.y + q[2]*ka.z + q[3]*ka.w
                    + q[4]*kb.x + q[5]*kb.y + q[6]*kb.z + q[7]*kb.w;
            d += __shfl_xor(d, 1);
            d += __shfl_xor(d, 2);
            float sc = d + rb[kj];
            float mn = fmaxf(m, sc);
            float co = __expf(m - mn);
            float pw = __expf(sc - mn);
            l = l * co + pw;
            const float4* vr = (const float4*)&Vs[n][sub * 8];
            float4 va = vr[0], vb = vr[1];
            acc[0] = acc[0]*co + pw*va.x;
            acc[1] = acc[1]*co + pw*va.y;
            acc[2] = acc[2]*co + pw*va.z;
            acc[3] = acc[3]*co + pw*va.w;
            acc[4] = acc[4]*co + pw*vb.x;
            acc[5] = acc[5]*co + pw*vb.y;
            acc[6] = acc[6]*co + pw*vb.z;
            acc[7] = acc[7]*co + pw*vb.w;
            m = mn;
        }
    }
    float rl = 1.f / l;
    float* op = out + (size_t)(pi * IMW + pj) * DIM + head * HD + sub * 8;
    float4 o0 = {acc[0]*rl, acc[1]*rl, acc[2]*rl, acc[3]*rl};
    float4 o1 = {acc[4]*rl, acc[5]*rl, acc[6]*rl, acc[7]*rl};
    *(float4*)op = o0;
    *(float4*)(op + 4) = o1;
}

extern "C" void kernel_launch(void* const* d_in, const int* in_sizes, int n_in,
                              void* d_out, int out_size, void* d_ws, size_t ws_size,
                              hipStream_t stream)
{
    const float* x      = (const float*)d_in[0];
    const float* qkv_w  = (const float*)d_in[1];
    const float* qkv_b  = (const float*)d_in[2];
    const float* proj_w = (const float*)d_in[3];
    const float* proj_b = (const float*)d_in[4];
    const float* rpb    = (const float*)d_in[5];
    const float* ln1_w  = (const float*)d_in[6];
    const float* ln1_b  = (const float*)d_in[7];
    const float* ln2_w  = (const float*)d_in[8];
    const float* ln2_b  = (const float*)d_in[9];
    const float* fc1_w  = (const float*)d_in[10];
    const float* fc1_b  = (const float*)d_in[11];
    const float* fc2_w  = (const float*)d_in[12];
    const float* fc2_b  = (const float*)d_in[13];
    const float* gamma1 = (const float*)d_in[14];
    const float* gamma2 = (const float*)d_in[15];
    const int*   quality= (const int*)d_in[16];
    float* out = (float*)d_out;

    float* h        = (float*)d_ws;                       // NPIX*DIM, reused for h2
    float* attn_out = h + (size_t)NPIX * DIM;             // NPIX*DIM
    float* qkvbuf   = attn_out + (size_t)NPIX * DIM;      // NPIX*576, reused as m1 (NPIX*768)

    // 1. LN1: x -> h
    ln_kernel<<<NPIX / 4, 256, 0, stream>>>(x, ln1_w, ln1_b, h);
    // 2. QKV GEMM: h @ qkv_w^T + qkv_b -> qkvbuf   (M=16384, N=576, K=192)
    gemm_kernel<<<dim3(NPIX / TM, 576 / TN), 256, 0, stream>>>(
        h, qkv_w, qkv_b, qkvbuf, nullptr, nullptr, nullptr, NPIX, 576, DIM, 0);
    // 3. neighborhood attention -> attn_out
    attn_kernel2<<<dim3(256, NHD), 256, 0, stream>>>(qkvbuf, rpb, attn_out);
    // 4. proj + residual: out = x + |g1|*(attn_out @ proj_w^T + proj_b)
    gemm_kernel<<<dim3(NPIX / TM, DIM / TN), 256, 0, stream>>>(
        attn_out, proj_w, proj_b, out, x, gamma1, quality, NPIX, DIM, DIM, 2);
    // 5. LN2: out -> h
    ln_kernel<<<NPIX / 4, 256, 0, stream>>>(out, ln2_w, ln2_b, h);
    // 6. FC1 + GELU: gelu(h @ fc1_w^T + fc1_b) -> m1   (N=768)
    gemm_kernel<<<dim3(NPIX / TM, HID / TN), 256, 0, stream>>>(
        h, fc1_w, fc1_b, qkvbuf, nullptr, nullptr, nullptr, NPIX, HID, DIM, 1);
    // 7. FC2 + residual: out = out + |g2|*(m1 @ fc2_w^T + fc2_b)   (K=768)
    gemm_kernel<<<dim3(NPIX / TM, DIM / TN), 256, 0, stream>>>(
        qkvbuf, fc2_w, fc2_b, out, out, gamma2, quality, NPIX, DIM, HID, 2);
}

// Round 3
// 238.010 us; speedup vs baseline: 2.3260x; 1.5229x over previous
//
#include <hip/hip_runtime.h>
#include <hip/hip_bf16.h>
#include <math.h>

#define DIM 192
#define NHD 6
#define HD 32
#define KSZ 7
#define HID 768
#define IMH 128
#define IMW 128
#define NPIX (IMH*IMW)
#define WIN 14

typedef __attribute__((ext_vector_type(8))) short short8;
typedef __attribute__((ext_vector_type(4))) float f32x4;

// ---------------- weight fp32->bf16 conversion (one kernel, 4 segments) ----------------
__global__ __launch_bounds__(256) void cvt_w(
    const float* __restrict__ q, const float* __restrict__ p,
    const float* __restrict__ f1, const float* __restrict__ f2,
    __hip_bfloat16* dq, __hip_bfloat16* dp, __hip_bfloat16* df1, __hip_bfloat16* df2)
{
    int b = blockIdx.x, t = threadIdx.x;
    const float* s; __hip_bfloat16* d; int idx;
    if (b < 432)       { s = q;  d = dq;  idx = b * 256 + t; }          // 576*192
    else if (b < 576)  { s = p;  d = dp;  idx = (b - 432) * 256 + t; }  // 192*192
    else if (b < 1152) { s = f1; d = df1; idx = (b - 576) * 256 + t; }  // 768*192
    else               { s = f2; d = df2; idx = (b - 1152) * 256 + t; } // 192*768
    d[idx] = __float2bfloat16(s[idx]);
}

// ---------------- LayerNorm: one wave per pixel, writes bf16 ----------------
__global__ __launch_bounds__(256) void ln_kernel(const float* __restrict__ x,
                                                 const float* __restrict__ w,
                                                 const float* __restrict__ b,
                                                 __hip_bfloat16* __restrict__ out)
{
    int wid  = (blockIdx.x * 256 + threadIdx.x) >> 6;
    int lane = threadIdx.x & 63;
    if (wid >= NPIX) return;
    const float* xp = x + (size_t)wid * DIM;
    float v0 = xp[lane], v1 = xp[lane + 64], v2 = xp[lane + 128];
    float s = v0 + v1 + v2;
    #pragma unroll
    for (int off = 32; off > 0; off >>= 1) s += __shfl_down(s, off);
    float mu = __shfl(s, 0) * (1.0f / DIM);
    float d0 = v0 - mu, d1 = v1 - mu, d2 = v2 - mu;
    float q = d0*d0 + d1*d1 + d2*d2;
    #pragma unroll
    for (int off = 32; off > 0; off >>= 1) q += __shfl_down(q, off);
    float rstd = rsqrtf(__shfl(q, 0) * (1.0f / DIM) + 1e-5f);
    __hip_bfloat16* op = out + (size_t)wid * DIM;
    op[lane]       = __float2bfloat16(d0 * rstd * w[lane]       + b[lane]);
    op[lane + 64]  = __float2bfloat16(d1 * rstd * w[lane + 64]  + b[lane + 64]);
    op[lane + 128] = __float2bfloat16(d2 * rstd * w[lane + 128] + b[lane + 128]);
}

// ---------------- MFMA bf16 GEMM: C[M,N] = A[M,K] @ W[N,K]^T + epilogue ----------------
// Tile 128x64, BK=64, 4 waves (2x2), 16x16x32 MFMA, global_load_lds staging,
// XOR-swizzled LDS (kgroup ^= row&7) to break the 128B-row-stride bank pathology.
// mode 0: +bias -> fp32    mode 1: gelu(+bias) -> bf16    mode 2: resid+|gamma|*(+bias) -> fp32
#define GTM 128
#define GTN 64
#define GBK 64

__device__ __forceinline__ void gl_lds16(const void* g, void* l) {
    __builtin_amdgcn_global_load_lds(
        (const __attribute__((address_space(1))) void*)g,
        (__attribute__((address_space(3))) void*)l, 16, 0, 0);
}

__global__ __launch_bounds__(256) void mfma_gemm(
    const __hip_bfloat16* A, const __hip_bfloat16* W, const float* bias,
    float* outf, __hip_bfloat16* outb, const float* resid,
    const float* gamma, const int* quality, int N, int K, int mode)
{
    __shared__ __hip_bfloat16 As[GTM * GBK];   // 16 KB
    __shared__ __hip_bfloat16 Bs[GTN * GBK];   // 8 KB
    int tid  = threadIdx.x;
    int wave = tid >> 6, lane = tid & 63;
    int m0 = blockIdx.x * GTM, n0 = blockIdx.y * GTN;
    int q = lane >> 4, col = lane & 15;
    int wm = (wave >> 1) * 64, wn = (wave & 1) * 32;

    f32x4 acc[4][2] = {};

    for (int k0 = 0; k0 < K; k0 += GBK) {
        // stage A: 1024 16B chunks; LDS slot c gets global kgroup (c&7)^(row&7)
        #pragma unroll
        for (int i = 0; i < 4; i++) {
            int c = i * 256 + tid;
            int r = c >> 3;
            int g = (c & 7) ^ (r & 7);
            gl_lds16(A + (size_t)(m0 + r) * K + k0 + g * 8,
                     (char*)As + (i * 256 + wave * 64) * 16);
        }
        #pragma unroll
        for (int i = 0; i < 2; i++) {
            int c = i * 256 + tid;
            int r = c >> 3;
            int g = (c & 7) ^ (r & 7);
            gl_lds16(W + (size_t)(n0 + r) * K + k0 + g * 8,
                     (char*)Bs + (i * 256 + wave * 64) * 16);
        }
        __syncthreads();

        #pragma unroll
        for (int kk = 0; kk < 2; kk++) {
            short8 af[4], bf[2];
            #pragma unroll
            for (int mi = 0; mi < 4; mi++) {
                int r = wm + mi * 16 + col;
                int g = (kk * 4 + q) ^ (r & 7);
                af[mi] = *(const short8*)&As[r * GBK + g * 8];
            }
            #pragma unroll
            for (int ni = 0; ni < 2; ni++) {
                int r = wn + ni * 16 + col;
                int g = (kk * 4 + q) ^ (r & 7);
                bf[ni] = *(const short8*)&Bs[r * GBK + g * 8];
            }
            #pragma unroll
            for (int mi = 0; mi < 4; mi++)
                #pragma unroll
                for (int ni = 0; ni < 2; ni++)
                    acc[mi][ni] = __builtin_amdgcn_mfma_f32_16x16x32_bf16(
                        af[mi], bf[ni], acc[mi][ni], 0, 0, 0);
        }
        __syncthreads();
    }

    int s = quality ? quality[0] - 1 : 0;
    #pragma unroll
    for (int mi = 0; mi < 4; mi++) {
        #pragma unroll
        for (int r = 0; r < 4; r++) {
            int m = m0 + wm + mi * 16 + q * 4 + r;
            #pragma unroll
            for (int ni = 0; ni < 2; ni++) {
                int n = n0 + wn + ni * 16 + col;
                float v = acc[mi][ni][r] + bias[n];
                if (mode == 0) {
                    outf[(size_t)m * N + n] = v;
                } else if (mode == 1) {
                    v = 0.5f * v * (1.0f + erff(v * 0.70710678118654752f));
                    outb[(size_t)m * N + n] = __float2bfloat16(v);
                } else {
                    float gm = fabsf(gamma[s * DIM + n]);
                    outf[(size_t)m * N + n] = resid[(size_t)m * N + n] + gm * v;
                }
            }
        }
    }
}

// ---------------- Neighborhood attention: block per (8x8 tile, head), bf16 out ----------------
__global__ __launch_bounds__(256) void attn_kernel2(
    const float* __restrict__ qkv, const float* __restrict__ rpb,
    __hip_bfloat16* __restrict__ out)
{
    __shared__ float Ks[WIN*WIN][36];
    __shared__ float Vs[WIN*WIN][36];
    __shared__ float rpbs[13 * 13];

    int head = blockIdx.y;
    int tile = blockIdx.x;
    int ti0 = (tile >> 4) * 8;
    int tj0 = (tile & 15) * 8;
    int wi0 = ti0 - 3; wi0 = wi0 < 0 ? 0 : (wi0 > IMH - WIN ? IMH - WIN : wi0);
    int wj0 = tj0 - 3; wj0 = wj0 < 0 ? 0 : (wj0 > IMW - WIN ? IMW - WIN : wj0);

    int tid = threadIdx.x;
    {
        int part = tid & 7;
        for (int r = tid >> 3; r < WIN * WIN; r += 32) {
            int gi = wi0 + r / WIN, gj = wj0 + r % WIN;
            const float* src = qkv + (size_t)(gi * IMW + gj) * 576 + DIM + head * HD + part * 4;
            float4 kv = *(const float4*)src;
            float4 vv = *(const float4*)(src + DIM);
            *(float4*)&Ks[r][part * 4] = kv;
            *(float4*)&Vs[r][part * 4] = vv;
        }
    }
    if (tid < 169) rpbs[tid] = rpb[head * 169 + tid];

    int p   = tid >> 2;
    int sub = tid & 3;
    int pi = ti0 + (p >> 3), pj = tj0 + (p & 7);
    int si = pi - 3; si = si < 0 ? 0 : (si > IMH - KSZ ? IMH - KSZ : si);
    int sj = pj - 3; sj = sj < 0 ? 0 : (sj > IMW - KSZ ? IMW - KSZ : sj);
    int bi = si - wi0, bj = sj - wj0;

    const float scale = 0.17677669529663687f;
    const float* qp = qkv + (size_t)(pi * IMW + pj) * 576 + head * HD + sub * 8;
    float4 q0 = *(const float4*)qp;
    float4 q1 = *(const float4*)(qp + 4);
    float q[8] = {q0.x*scale, q0.y*scale, q0.z*scale, q0.w*scale,
                  q1.x*scale, q1.y*scale, q1.z*scale, q1.w*scale};

    __syncthreads();

    float m = -1e30f, l = 0.f;
    float acc[8] = {};
    #pragma unroll
    for (int ki = 0; ki < KSZ; ki++) {
        int rbase = (bi + ki) * WIN + bj;
        const float* rb = &rpbs[(si + ki - pi + 6) * 13 + (sj - pj + 6)];
        #pragma unroll
        for (int kj = 0; kj < KSZ; kj++) {
            int n = rbase + kj;
            const float4* kr = (const float4*)&Ks[n][sub * 8];
            float4 ka = kr[0], kb = kr[1];
            float d = q[0]*ka.x + q[1]*ka.y + q[2]*ka.z + q[3]*ka.w
                    + q[4]*kb.x + q[5]*kb.y + q[6]*kb.z + q[7]*kb.w;
            d += __shfl_xor(d, 1);
            d += __shfl_xor(d, 2);
            float sc = d + rb[kj];
            float mn = fmaxf(m, sc);
            float co = __expf(m - mn);
            float pw = __expf(sc - mn);
            l = l * co + pw;
            const float4* vr = (const float4*)&Vs[n][sub * 8];
            float4 va = vr[0], vb = vr[1];
            acc[0] = acc[0]*co + pw*va.x;
            acc[1] = acc[1]*co + pw*va.y;
            acc[2] = acc[2]*co + pw*va.z;
            acc[3] = acc[3]*co + pw*va.w;
            acc[4] = acc[4]*co + pw*vb.x;
            acc[5] = acc[5]*co + pw*vb.y;
            acc[6] = acc[6]*co + pw*vb.z;
            acc[7] = acc[7]*co + pw*vb.w;
            m = mn;
        }
    }
    float rl = 1.f / l;
    __hip_bfloat16* op = out + (size_t)(pi * IMW + pj) * DIM + head * HD + sub * 8;
    #pragma unroll
    for (int d = 0; d < 8; d++) op[d] = __float2bfloat16(acc[d] * rl);
}

extern "C" void kernel_launch(void* const* d_in, const int* in_sizes, int n_in,
                              void* d_out, int out_size, void* d_ws, size_t ws_size,
                              hipStream_t stream)
{
    const float* x      = (const float*)d_in[0];
    const float* qkv_w  = (const float*)d_in[1];
    const float* qkv_b  = (const float*)d_in[2];
    const float* proj_w = (const float*)d_in[3];
    const float* proj_b = (const float*)d_in[4];
    const float* rpb    = (const float*)d_in[5];
    const float* ln1_w  = (const float*)d_in[6];
    const float* ln1_b  = (const float*)d_in[7];
    const float* ln2_w  = (const float*)d_in[8];
    const float* ln2_b  = (const float*)d_in[9];
    const float* fc1_w  = (const float*)d_in[10];
    const float* fc1_b  = (const float*)d_in[11];
    const float* fc2_w  = (const float*)d_in[12];
    const float* fc2_b  = (const float*)d_in[13];
    const float* gamma1 = (const float*)d_in[14];
    const float* gamma2 = (const float*)d_in[15];
    const int*   quality= (const int*)d_in[16];
    float* out = (float*)d_out;

    // workspace layout (bytes):
    //   [0, 37748736)          qkv fp32 (16384*576*4)  -- later aliased by m1 bf16 (25.2MB)
    //   [37748736, 44040192)   h bf16   (16384*192*2)
    //   [44040192, 50331648)   attn bf16(16384*192*2)
    //   [50331648, ...)        bf16 weights
    char* ws = (char*)d_ws;
    float*          qkvbuf = (float*)ws;
    __hip_bfloat16* m1     = (__hip_bfloat16*)ws;
    __hip_bfloat16* h      = (__hip_bfloat16*)(ws + 37748736);
    __hip_bfloat16* attn_b = (__hip_bfloat16*)(ws + 44040192);
    __hip_bfloat16* wq     = (__hip_bfloat16*)(ws + 50331648);
    __hip_bfloat16* wp     = (__hip_bfloat16*)(ws + 50552832);
    __hip_bfloat16* wf1    = (__hip_bfloat16*)(ws + 50626560);
    __hip_bfloat16* wf2    = (__hip_bfloat16*)(ws + 50921472);

    // 0. convert weights to bf16
    cvt_w<<<1728, 256, 0, stream>>>(qkv_w, proj_w, fc1_w, fc2_w, wq, wp, wf1, wf2);
    // 1. LN1: x -> h (bf16)
    ln_kernel<<<NPIX / 4, 256, 0, stream>>>(x, ln1_w, ln1_b, h);
    // 2. QKV GEMM: h @ wq^T + qkv_b -> qkvbuf fp32   (N=576, K=192)
    mfma_gemm<<<dim3(NPIX / GTM, 576 / GTN), 256, 0, stream>>>(
        h, wq, qkv_b, qkvbuf, nullptr, nullptr, nullptr, nullptr, 576, DIM, 0);
    // 3. neighborhood attention -> attn_b (bf16)
    attn_kernel2<<<dim3(256, NHD), 256, 0, stream>>>(qkvbuf, rpb, attn_b);
    // 4. proj + residual: out = x + |g1|*(attn @ wp^T + proj_b)   (N=192, K=192)
    mfma_gemm<<<dim3(NPIX / GTM, DIM / GTN), 256, 0, stream>>>(
        attn_b, wp, proj_b, out, nullptr, x, gamma1, quality, DIM, DIM, 2);
    // 5. LN2: out -> h (bf16)
    ln_kernel<<<NPIX / 4, 256, 0, stream>>>(out, ln2_w, ln2_b, h);
    // 6. FC1 + GELU: gelu(h @ wf1^T + fc1_b) -> m1 (bf16)   (N=768, K=192)
    mfma_gemm<<<dim3(NPIX / GTM, HID / GTN), 256, 0, stream>>>(
        h, wf1, fc1_b, nullptr, m1, nullptr, nullptr, nullptr, HID, DIM, 1);
    // 7. FC2 + residual: out += |g2|*(m1 @ wf2^T + fc2_b)   (N=192, K=768)
    mfma_gemm<<<dim3(NPIX / GTM, DIM / GTN), 256, 0, stream>>>(
        m1, wf2, fc2_b, out, nullptr, out, gamma2, quality, DIM, HID, 2);
}

// Round 4
// 228.761 us; speedup vs baseline: 2.4201x; 1.0404x over previous
//
#include <hip/hip_runtime.h>
#include <hip/hip_bf16.h>
#include <math.h>

#define DIM 192
#define NHD 6
#define HD 32
#define KSZ 7
#define HID 768
#define IMH 128
#define IMW 128
#define NPIX (IMH*IMW)
#define WIN 14
#define KPAD 40   // LDS row stride in halves (80B): 8 consecutive rows cover all 32 banks

typedef __attribute__((ext_vector_type(8))) short short8;
typedef __attribute__((ext_vector_type(4))) float f32x4;

// ---------------- weight fp32->bf16 conversion (one kernel, 4 segments) ----------------
__global__ __launch_bounds__(256) void cvt_w(
    const float* __restrict__ q, const float* __restrict__ p,
    const float* __restrict__ f1, const float* __restrict__ f2,
    __hip_bfloat16* dq, __hip_bfloat16* dp, __hip_bfloat16* df1, __hip_bfloat16* df2)
{
    int b = blockIdx.x, t = threadIdx.x;
    const float* s; __hip_bfloat16* d; int idx;
    if (b < 432)       { s = q;  d = dq;  idx = b * 256 + t; }
    else if (b < 576)  { s = p;  d = dp;  idx = (b - 432) * 256 + t; }
    else if (b < 1152) { s = f1; d = df1; idx = (b - 576) * 256 + t; }
    else               { s = f2; d = df2; idx = (b - 1152) * 256 + t; }
    d[idx] = __float2bfloat16(s[idx]);
}

// ---------------- LayerNorm: one wave per pixel, writes bf16 ----------------
__global__ __launch_bounds__(256) void ln_kernel(const float* __restrict__ x,
                                                 const float* __restrict__ w,
                                                 const float* __restrict__ b,
                                                 __hip_bfloat16* __restrict__ out)
{
    int wid  = (blockIdx.x * 256 + threadIdx.x) >> 6;
    int lane = threadIdx.x & 63;
    if (wid >= NPIX) return;
    const float* xp = x + (size_t)wid * DIM;
    float v0 = xp[lane], v1 = xp[lane + 64], v2 = xp[lane + 128];
    float s = v0 + v1 + v2;
    #pragma unroll
    for (int off = 32; off > 0; off >>= 1) s += __shfl_down(s, off);
    float mu = __shfl(s, 0) * (1.0f / DIM);
    float d0 = v0 - mu, d1 = v1 - mu, d2 = v2 - mu;
    float q = d0*d0 + d1*d1 + d2*d2;
    #pragma unroll
    for (int off = 32; off > 0; off >>= 1) q += __shfl_down(q, off);
    float rstd = rsqrtf(__shfl(q, 0) * (1.0f / DIM) + 1e-5f);
    __hip_bfloat16* op = out + (size_t)wid * DIM;
    op[lane]       = __float2bfloat16(d0 * rstd * w[lane]       + b[lane]);
    op[lane + 64]  = __float2bfloat16(d1 * rstd * w[lane + 64]  + b[lane + 64]);
    op[lane + 128] = __float2bfloat16(d2 * rstd * w[lane + 128] + b[lane + 128]);
}

// ---------------- MFMA bf16 GEMM: C[M,N] = A[M,K] @ W[N,K]^T + epilogue ----------------
// mode 0: qkv split -> q fp32 planar (scaled), k/v bf16 planar
// mode 1: gelu(+bias) -> bf16       mode 2: resid + |gamma|*(+bias) -> fp32
#define GTM 128
#define GTN 64
#define GBK 64

__device__ __forceinline__ void gl_lds16(const void* g, void* l) {
    __builtin_amdgcn_global_load_lds(
        (const __attribute__((address_space(1))) void*)g,
        (__attribute__((address_space(3))) void*)l, 16, 0, 0);
}

__global__ __launch_bounds__(256) void mfma_gemm(
    const __hip_bfloat16* A, const __hip_bfloat16* W, const float* bias,
    float* outf, __hip_bfloat16* outb, __hip_bfloat16* kb, __hip_bfloat16* vb,
    const float* resid, const float* gamma, const int* quality,
    int N, int K, int mode)
{
    __shared__ __hip_bfloat16 As[GTM * GBK];
    __shared__ __hip_bfloat16 Bs[GTN * GBK];
    int tid  = threadIdx.x;
    int wave = tid >> 6, lane = tid & 63;
    int m0 = blockIdx.x * GTM, n0 = blockIdx.y * GTN;
    int q = lane >> 4, col = lane & 15;
    int wm = (wave >> 1) * 64, wn = (wave & 1) * 32;

    f32x4 acc[4][2] = {};

    for (int k0 = 0; k0 < K; k0 += GBK) {
        #pragma unroll
        for (int i = 0; i < 4; i++) {
            int c = i * 256 + tid;
            int r = c >> 3;
            int g = (c & 7) ^ (r & 7);
            gl_lds16(A + (size_t)(m0 + r) * K + k0 + g * 8,
                     (char*)As + (i * 256 + wave * 64) * 16);
        }
        #pragma unroll
        for (int i = 0; i < 2; i++) {
            int c = i * 256 + tid;
            int r = c >> 3;
            int g = (c & 7) ^ (r & 7);
            gl_lds16(W + (size_t)(n0 + r) * K + k0 + g * 8,
                     (char*)Bs + (i * 256 + wave * 64) * 16);
        }
        __syncthreads();

        #pragma unroll
        for (int kk = 0; kk < 2; kk++) {
            short8 af[4], bf[2];
            #pragma unroll
            for (int mi = 0; mi < 4; mi++) {
                int r = wm + mi * 16 + col;
                int g = (kk * 4 + q) ^ (r & 7);
                af[mi] = *(const short8*)&As[r * GBK + g * 8];
            }
            #pragma unroll
            for (int ni = 0; ni < 2; ni++) {
                int r = wn + ni * 16 + col;
                int g = (kk * 4 + q) ^ (r & 7);
                bf[ni] = *(const short8*)&Bs[r * GBK + g * 8];
            }
            #pragma unroll
            for (int mi = 0; mi < 4; mi++)
                #pragma unroll
                for (int ni = 0; ni < 2; ni++)
                    acc[mi][ni] = __builtin_amdgcn_mfma_f32_16x16x32_bf16(
                        af[mi], bf[ni], acc[mi][ni], 0, 0, 0);
        }
        __syncthreads();
    }

    int s = quality ? quality[0] - 1 : 0;
    #pragma unroll
    for (int mi = 0; mi < 4; mi++) {
        #pragma unroll
        for (int r = 0; r < 4; r++) {
            int m = m0 + wm + mi * 16 + q * 4 + r;
            #pragma unroll
            for (int ni = 0; ni < 2; ni++) {
                int n = n0 + wn + ni * 16 + col;
                float v = acc[mi][ni][r] + bias[n];
                if (mode == 0) {
                    int h18 = n >> 5;            // 0..17
                    int sel = h18 / 6;           // 0=q 1=k 2=v
                    int head = h18 - sel * 6;
                    size_t idx = ((size_t)head * NPIX + m) * 32 + (n & 31);
                    if (sel == 0)      outf[idx] = v * 0.17677669529663687f;
                    else if (sel == 1) kb[idx] = __float2bfloat16(v);
                    else               vb[idx] = __float2bfloat16(v);
                } else if (mode == 1) {
                    v = 0.5f * v * (1.0f + erff(v * 0.70710678118654752f));
                    outb[(size_t)m * N + n] = __float2bfloat16(v);
                } else {
                    float gm = fabsf(gamma[s * DIM + n]);
                    outf[(size_t)m * N + n] = resid[(size_t)m * N + n] + gm * v;
                }
            }
        }
    }
}

// ---------------- Neighborhood attention v3: bf16 K/V in padded LDS ----------------
__device__ __forceinline__ void unpack8(const __hip_bfloat16* ptr, float* f) {
    short8 s8 = *(const short8*)ptr;
    union { short8 v; unsigned u[4]; } c; c.v = s8;
    #pragma unroll
    for (int w = 0; w < 4; w++) {
        f[2*w]   = __uint_as_float(c.u[w] << 16);
        f[2*w+1] = __uint_as_float(c.u[w] & 0xffff0000u);
    }
}

__global__ __launch_bounds__(256, 4) void attn_kernel3(
    const float* __restrict__ qbuf, const __hip_bfloat16* __restrict__ kbuf,
    const __hip_bfloat16* __restrict__ vbuf, const float* __restrict__ rpb,
    __hip_bfloat16* __restrict__ out)
{
    __shared__ __hip_bfloat16 Ks[WIN * WIN * KPAD];   // 15.7 KB
    __shared__ __hip_bfloat16 Vs[WIN * WIN * KPAD];   // 15.7 KB
    __shared__ float rpbs[169];

    int head = blockIdx.y;
    int tile = blockIdx.x;
    int ti0 = (tile >> 4) * 8;
    int tj0 = (tile & 15) * 8;
    int wi0 = ti0 - 3; wi0 = wi0 < 0 ? 0 : (wi0 > IMH - WIN ? IMH - WIN : wi0);
    int wj0 = tj0 - 3; wj0 = wj0 < 0 ? 0 : (wj0 > IMW - WIN ? IMW - WIN : wj0);

    int tid = threadIdx.x;
    const size_t hbase = (size_t)head * NPIX;

    // stage K/V: 14 window rows x 14 pixels x 32 bf16, 4 chunks(16B)/pixel
    for (int c = tid; c < 784; c += 256) {
        int i = c / 56, part = c - i * 56;           // window row, chunk in row
        int n = i * WIN + (part >> 2);               // window pixel index
        int dp = part & 3;
        size_t goff = (hbase + (size_t)(wi0 + i) * IMW + wj0) * 32 + part * 8;
        short8 kk = *(const short8*)(kbuf + goff);
        short8 vv = *(const short8*)(vbuf + goff);
        *(short8*)&Ks[n * KPAD + dp * 8] = kk;
        *(short8*)&Vs[n * KPAD + dp * 8] = vv;
    }
    if (tid < 169) rpbs[tid] = rpb[head * 169 + tid];

    int p   = tid >> 2;
    int sub = tid & 3;
    int pi = ti0 + (p >> 3), pj = tj0 + (p & 7);
    int si = pi - 3; si = si < 0 ? 0 : (si > IMH - KSZ ? IMH - KSZ : si);
    int sj = pj - 3; sj = sj < 0 ? 0 : (sj > IMW - KSZ ? IMW - KSZ : sj);
    int bi = si - wi0, bj = sj - wj0;

    // q: fp32, already scaled, planar [head][pix][32]
    const float4* qp = (const float4*)(qbuf + (hbase + (size_t)(pi * IMW + pj)) * 32 + sub * 8);
    float4 q0 = qp[0], q1 = qp[1];
    float q[8] = {q0.x, q0.y, q0.z, q0.w, q1.x, q1.y, q1.z, q1.w};

    __syncthreads();

    float m = -1e30f, l = 0.f;
    float acc[8] = {};
    #pragma unroll
    for (int ki = 0; ki < KSZ; ki++) {
        int rbase = (bi + ki) * WIN + bj;
        const float* rb = &rpbs[(si + ki - pi + 6) * 13 + (sj - pj + 6)];
        #pragma unroll
        for (int kj = 0; kj < KSZ; kj++) {
            int n = rbase + kj;
            float kf[8];
            unpack8(&Ks[n * KPAD + sub * 8], kf);
            float d = q[0]*kf[0] + q[1]*kf[1] + q[2]*kf[2] + q[3]*kf[3]
                    + q[4]*kf[4] + q[5]*kf[5] + q[6]*kf[6] + q[7]*kf[7];
            d += __shfl_xor(d, 1);
            d += __shfl_xor(d, 2);
            float sc = d + rb[kj];
            float mn = fmaxf(m, sc);
            float co = __expf(m - mn);
            float pw = __expf(sc - mn);
            l = l * co + pw;
            float vf[8];
            unpack8(&Vs[n * KPAD + sub * 8], vf);
            #pragma unroll
            for (int e = 0; e < 8; e++) acc[e] = acc[e] * co + pw * vf[e];
            m = mn;
        }
    }
    float rl = 1.f / l;
    __hip_bfloat16* op = out + (size_t)(pi * IMW + pj) * DIM + head * HD + sub * 8;
    #pragma unroll
    for (int e = 0; e < 8; e++) op[e] = __float2bfloat16(acc[e] * rl);
}

extern "C" void kernel_launch(void* const* d_in, const int* in_sizes, int n_in,
                              void* d_out, int out_size, void* d_ws, size_t ws_size,
                              hipStream_t stream)
{
    const float* x      = (const float*)d_in[0];
    const float* qkv_w  = (const float*)d_in[1];
    const float* qkv_b  = (const float*)d_in[2];
    const float* proj_w = (const float*)d_in[3];
    const float* proj_b = (const float*)d_in[4];
    const float* rpb    = (const float*)d_in[5];
    const float* ln1_w  = (const float*)d_in[6];
    const float* ln1_b  = (const float*)d_in[7];
    const float* ln2_w  = (const float*)d_in[8];
    const float* ln2_b  = (const float*)d_in[9];
    const float* fc1_w  = (const float*)d_in[10];
    const float* fc1_b  = (const float*)d_in[11];
    const float* fc2_w  = (const float*)d_in[12];
    const float* fc2_b  = (const float*)d_in[13];
    const float* gamma1 = (const float*)d_in[14];
    const float* gamma2 = (const float*)d_in[15];
    const int*   quality= (const int*)d_in[16];
    float* out = (float*)d_out;

    // workspace layout (bytes):
    //   [0, 12582912)          qbuf fp32 planar [head][pix][32]   (12.58MB)
    //   [12582912, 18874368)   kbuf bf16 planar                    (6.29MB)
    //   [18874368, 25165824)   vbuf bf16 planar                    (6.29MB)
    //   [0, 25165824)          (aliased later) m1 bf16 16384*768
    //   [37748736, 44040192)   h bf16
    //   [44040192, 50331648)   attn bf16
    //   [50331648, ...)        bf16 weights
    char* ws = (char*)d_ws;
    float*          qbuf   = (float*)ws;
    __hip_bfloat16* kbuf   = (__hip_bfloat16*)(ws + 12582912);
    __hip_bfloat16* vbuf   = (__hip_bfloat16*)(ws + 18874368);
    __hip_bfloat16* m1     = (__hip_bfloat16*)ws;
    __hip_bfloat16* h      = (__hip_bfloat16*)(ws + 37748736);
    __hip_bfloat16* attn_b = (__hip_bfloat16*)(ws + 44040192);
    __hip_bfloat16* wq     = (__hip_bfloat16*)(ws + 50331648);
    __hip_bfloat16* wp     = (__hip_bfloat16*)(ws + 50552832);
    __hip_bfloat16* wf1    = (__hip_bfloat16*)(ws + 50626560);
    __hip_bfloat16* wf2    = (__hip_bfloat16*)(ws + 50921472);

    // 0. convert weights to bf16
    cvt_w<<<1728, 256, 0, stream>>>(qkv_w, proj_w, fc1_w, fc2_w, wq, wp, wf1, wf2);
    // 1. LN1: x -> h (bf16)
    ln_kernel<<<NPIX / 4, 256, 0, stream>>>(x, ln1_w, ln1_b, h);
    // 2. QKV GEMM: h @ wq^T + qkv_b -> q fp32 planar (scaled) + k/v bf16 planar
    mfma_gemm<<<dim3(NPIX / GTM, 576 / GTN), 256, 0, stream>>>(
        h, wq, qkv_b, qbuf, nullptr, kbuf, vbuf, nullptr, nullptr, nullptr, 576, DIM, 0);
    // 3. neighborhood attention -> attn_b (bf16)
    attn_kernel3<<<dim3(256, NHD), 256, 0, stream>>>(qbuf, kbuf, vbuf, rpb, attn_b);
    // 4. proj + residual: out = x + |g1|*(attn @ wp^T + proj_b)
    mfma_gemm<<<dim3(NPIX / GTM, DIM / GTN), 256, 0, stream>>>(
        attn_b, wp, proj_b, out, nullptr, nullptr, nullptr, x, gamma1, quality, DIM, DIM, 2);
    // 5. LN2: out -> h (bf16)
    ln_kernel<<<NPIX / 4, 256, 0, stream>>>(out, ln2_w, ln2_b, h);
    // 6. FC1 + GELU: gelu(h @ wf1^T + fc1_b) -> m1 (bf16)
    mfma_gemm<<<dim3(NPIX / GTM, HID / GTN), 256, 0, stream>>>(
        h, wf1, fc1_b, nullptr, m1, nullptr, nullptr, nullptr, nullptr, nullptr, HID, DIM, 1);
    // 7. FC2 + residual: out += |g2|*(m1 @ wf2^T + fc2_b)
    mfma_gemm<<<dim3(NPIX / GTM, DIM / GTN), 256, 0, stream>>>(
        m1, wf2, fc2_b, out, nullptr, nullptr, nullptr, out, gamma2, quality, DIM, HID, 2);
}

// Round 5
// 215.106 us; speedup vs baseline: 2.5737x; 1.0635x over previous
//
#include <hip/hip_runtime.h>
#include <hip/hip_bf16.h>
#include <math.h>

#define DIM 192
#define NHD 6
#define HD 32
#define KSZ 7
#define HID 768
#define IMH 128
#define IMW 128
#define NPIX (IMH*IMW)
#define WIN 14
#define KPAD 40

typedef __attribute__((ext_vector_type(8))) short short8;
typedef __attribute__((ext_vector_type(4))) float f32x4;

// ---------------- fused: weight fp32->bf16 (blocks 0..1727) + LN1 (blocks 1728..) ----------------
__global__ __launch_bounds__(256) void cvt_ln1(
    const float* __restrict__ qw, const float* __restrict__ pw,
    const float* __restrict__ f1, const float* __restrict__ f2,
    __hip_bfloat16* dq, __hip_bfloat16* dp, __hip_bfloat16* df1, __hip_bfloat16* df2,
    const float* __restrict__ x, const float* __restrict__ w, const float* __restrict__ b,
    __hip_bfloat16* __restrict__ hout)
{
    int blk = blockIdx.x, t = threadIdx.x;
    if (blk < 1728) {
        const float* s; __hip_bfloat16* d; int idx;
        if (blk < 432)       { s = qw; d = dq;  idx = blk * 256 + t; }
        else if (blk < 576)  { s = pw; d = dp;  idx = (blk - 432) * 256 + t; }
        else if (blk < 1152) { s = f1; d = df1; idx = (blk - 576) * 256 + t; }
        else                 { s = f2; d = df2; idx = (blk - 1152) * 256 + t; }
        d[idx] = __float2bfloat16(s[idx]);
        return;
    }
    int wid  = ((blk - 1728) * 256 + t) >> 6;
    int lane = t & 63;
    const float* xp = x + (size_t)wid * DIM;
    float v0 = xp[lane], v1 = xp[lane + 64], v2 = xp[lane + 128];
    float s = v0 + v1 + v2;
    #pragma unroll
    for (int off = 32; off > 0; off >>= 1) s += __shfl_down(s, off);
    float mu = __shfl(s, 0) * (1.0f / DIM);
    float d0 = v0 - mu, d1 = v1 - mu, d2 = v2 - mu;
    float q = d0*d0 + d1*d1 + d2*d2;
    #pragma unroll
    for (int off = 32; off > 0; off >>= 1) q += __shfl_down(q, off);
    float rstd = rsqrtf(__shfl(q, 0) * (1.0f / DIM) + 1e-5f);
    __hip_bfloat16* op = hout + (size_t)wid * DIM;
    op[lane]       = __float2bfloat16(d0 * rstd * w[lane]       + b[lane]);
    op[lane + 64]  = __float2bfloat16(d1 * rstd * w[lane + 64]  + b[lane + 64]);
    op[lane + 128] = __float2bfloat16(d2 * rstd * w[lane + 128] + b[lane + 128]);
}

__device__ __forceinline__ void gl_lds16(const void* g, void* l) {
    __builtin_amdgcn_global_load_lds(
        (const __attribute__((address_space(1))) void*)g,
        (__attribute__((address_space(3))) void*)l, 16, 0, 0);
}

// ---------------- MFMA bf16 GEMM 128x64 tile: QKV-split (mode 0) / GELU (mode 1) ----------------
#define GTM 128
#define GTN 64
#define GBK 64

__global__ __launch_bounds__(256) void mfma_gemm(
    const __hip_bfloat16* A, const __hip_bfloat16* W, const float* bias,
    float* outf, __hip_bfloat16* outb, __hip_bfloat16* kb, __hip_bfloat16* vb,
    int N, int K, int mode)
{
    __shared__ __hip_bfloat16 As[GTM * GBK];
    __shared__ __hip_bfloat16 Bs[GTN * GBK];
    int tid  = threadIdx.x;
    int wave = tid >> 6, lane = tid & 63;
    int m0 = blockIdx.x * GTM, n0 = blockIdx.y * GTN;
    int q = lane >> 4, col = lane & 15;
    int wm = (wave >> 1) * 64, wn = (wave & 1) * 32;

    f32x4 acc[4][2] = {};

    for (int k0 = 0; k0 < K; k0 += GBK) {
        #pragma unroll
        for (int i = 0; i < 4; i++) {
            int c = i * 256 + tid;
            int r = c >> 3;
            int g = (c & 7) ^ (r & 7);
            gl_lds16(A + (size_t)(m0 + r) * K + k0 + g * 8,
                     (char*)As + (i * 256 + wave * 64) * 16);
        }
        #pragma unroll
        for (int i = 0; i < 2; i++) {
            int c = i * 256 + tid;
            int r = c >> 3;
            int g = (c & 7) ^ (r & 7);
            gl_lds16(W + (size_t)(n0 + r) * K + k0 + g * 8,
                     (char*)Bs + (i * 256 + wave * 64) * 16);
        }
        __syncthreads();

        #pragma unroll
        for (int kk = 0; kk < 2; kk++) {
            short8 af[4], bf[2];
            #pragma unroll
            for (int mi = 0; mi < 4; mi++) {
                int r = wm + mi * 16 + col;
                int g = (kk * 4 + q) ^ (r & 7);
                af[mi] = *(const short8*)&As[r * GBK + g * 8];
            }
            #pragma unroll
            for (int ni = 0; ni < 2; ni++) {
                int r = wn + ni * 16 + col;
                int g = (kk * 4 + q) ^ (r & 7);
                bf[ni] = *(const short8*)&Bs[r * GBK + g * 8];
            }
            #pragma unroll
            for (int mi = 0; mi < 4; mi++)
                #pragma unroll
                for (int ni = 0; ni < 2; ni++)
                    acc[mi][ni] = __builtin_amdgcn_mfma_f32_16x16x32_bf16(
                        af[mi], bf[ni], acc[mi][ni], 0, 0, 0);
        }
        __syncthreads();
    }

    #pragma unroll
    for (int mi = 0; mi < 4; mi++) {
        #pragma unroll
        for (int r = 0; r < 4; r++) {
            int m = m0 + wm + mi * 16 + q * 4 + r;
            #pragma unroll
            for (int ni = 0; ni < 2; ni++) {
                int n = n0 + wn + ni * 16 + col;
                float v = acc[mi][ni][r] + bias[n];
                if (mode == 0) {
                    int h18 = n >> 5;
                    int sel = h18 / 6;
                    int head = h18 - sel * 6;
                    size_t idx = ((size_t)head * NPIX + m) * 32 + (n & 31);
                    if (sel == 0)      outf[idx] = v * 0.17677669529663687f;
                    else if (sel == 1) kb[idx] = __float2bfloat16(v);
                    else               vb[idx] = __float2bfloat16(v);
                } else {
                    v = 0.5f * v * (1.0f + erff(v * 0.70710678118654752f));
                    outb[(size_t)m * N + n] = __float2bfloat16(v);
                }
            }
        }
    }
}

// ---------------- row GEMM: 64 rows x all 192 cols per block; resid+|gamma| epilogue ----------------
// withln=1: additionally LayerNorm each full row and write h bf16 (fuses LN2 into proj)
#define RBK 64
__global__ __launch_bounds__(256) void row_gemm(
    const __hip_bfloat16* A, const __hip_bfloat16* W, const float* bias,
    float* outf, __hip_bfloat16* hb, const float* resid,
    const float* gamma, const int* quality,
    const float* lnw, const float* lnb, int K, int withln)
{
    __shared__ __hip_bfloat16 As[64 * RBK];     // 8 KB
    __shared__ __hip_bfloat16 Bs[192 * RBK];    // 24 KB
    int tid = threadIdx.x;
    int wave = tid >> 6, lane = tid & 63;
    int q = lane >> 4, col = lane & 15;
    int m0 = blockIdx.x * 64;

    f32x4 acc[12] = {};
    for (int k0 = 0; k0 < K; k0 += RBK) {
        #pragma unroll
        for (int i = 0; i < 2; i++) {
            int c = i * 256 + tid;
            int r = c >> 3;
            int g = (c & 7) ^ (r & 7);
            gl_lds16(A + (size_t)(m0 + r) * K + k0 + g * 8,
                     (char*)As + (i * 256 + wave * 64) * 16);
        }
        #pragma unroll
        for (int i = 0; i < 6; i++) {
            int c = i * 256 + tid;
            int r = c >> 3;
            int g = (c & 7) ^ (r & 7);
            gl_lds16(W + (size_t)r * K + k0 + g * 8,
                     (char*)Bs + (i * 256 + wave * 64) * 16);
        }
        __syncthreads();
        #pragma unroll
        for (int kk = 0; kk < 2; kk++) {
            int rA = wave * 16 + col;
            short8 af = *(const short8*)&As[rA * RBK + (((kk * 4 + q) ^ (rA & 7)) * 8)];
            #pragma unroll
            for (int f = 0; f < 12; f++) {
                int rB = f * 16 + col;
                short8 bf = *(const short8*)&Bs[rB * RBK + (((kk * 4 + q) ^ (rB & 7)) * 8)];
                acc[f] = __builtin_amdgcn_mfma_f32_16x16x32_bf16(af, bf, acc[f], 0, 0, 0);
            }
        }
        __syncthreads();
    }

    int s = quality[0] - 1;
    float v[12][4];
    #pragma unroll
    for (int f = 0; f < 12; f++) {
        int n = f * 16 + col;
        float bi = bias[n];
        float g = fabsf(gamma[s * DIM + n]);
        #pragma unroll
        for (int r = 0; r < 4; r++) {
            int m = m0 + wave * 16 + q * 4 + r;
            v[f][r] = resid[(size_t)m * DIM + n] + g * (acc[f][r] + bi);
            outf[(size_t)m * DIM + n] = v[f][r];
        }
    }
    if (withln) {
        float sm[4] = {}, sq[4] = {};
        #pragma unroll
        for (int f = 0; f < 12; f++)
            #pragma unroll
            for (int r = 0; r < 4; r++) { sm[r] += v[f][r]; sq[r] += v[f][r] * v[f][r]; }
        #pragma unroll
        for (int off = 1; off <= 8; off <<= 1) {
            #pragma unroll
            for (int r = 0; r < 4; r++) {
                sm[r] += __shfl_xor(sm[r], off);
                sq[r] += __shfl_xor(sq[r], off);
            }
        }
        float mu[4], rstd[4];
        #pragma unroll
        for (int r = 0; r < 4; r++) {
            mu[r] = sm[r] * (1.0f / DIM);
            float var = sq[r] * (1.0f / DIM) - mu[r] * mu[r];
            rstd[r] = rsqrtf(var + 1e-5f);
        }
        #pragma unroll
        for (int f = 0; f < 12; f++) {
            int n = f * 16 + col;
            float lw = lnw[n], lb = lnb[n];
            #pragma unroll
            for (int r = 0; r < 4; r++) {
                int m = m0 + wave * 16 + q * 4 + r;
                hb[(size_t)m * DIM + n] =
                    __float2bfloat16((v[f][r] - mu[r]) * rstd[r] * lw + lb);
            }
        }
    }
}

// ---------------- Neighborhood attention: bf16 K/V in padded LDS ----------------
__device__ __forceinline__ void unpack8(const __hip_bfloat16* ptr, float* f) {
    short8 s8 = *(const short8*)ptr;
    union { short8 v; unsigned u[4]; } c; c.v = s8;
    #pragma unroll
    for (int w = 0; w < 4; w++) {
        f[2*w]   = __uint_as_float(c.u[w] << 16);
        f[2*w+1] = __uint_as_float(c.u[w] & 0xffff0000u);
    }
}

__global__ __launch_bounds__(256, 4) void attn_kernel3(
    const float* __restrict__ qbuf, const __hip_bfloat16* __restrict__ kbuf,
    const __hip_bfloat16* __restrict__ vbuf, const float* __restrict__ rpb,
    __hip_bfloat16* __restrict__ out)
{
    __shared__ __hip_bfloat16 Ks[WIN * WIN * KPAD];
    __shared__ __hip_bfloat16 Vs[WIN * WIN * KPAD];
    __shared__ float rpbs[169];

    int head = blockIdx.y;
    int tile = blockIdx.x;
    int ti0 = (tile >> 4) * 8;
    int tj0 = (tile & 15) * 8;
    int wi0 = ti0 - 3; wi0 = wi0 < 0 ? 0 : (wi0 > IMH - WIN ? IMH - WIN : wi0);
    int wj0 = tj0 - 3; wj0 = wj0 < 0 ? 0 : (wj0 > IMW - WIN ? IMW - WIN : wj0);

    int tid = threadIdx.x;
    const size_t hbase = (size_t)head * NPIX;

    for (int c = tid; c < 784; c += 256) {
        int i = c / 56, part = c - i * 56;
        int n = i * WIN + (part >> 2);
        int dp = part & 3;
        size_t goff = (hbase + (size_t)(wi0 + i) * IMW + wj0) * 32 + part * 8;
        short8 kk = *(const short8*)(kbuf + goff);
        short8 vv = *(const short8*)(vbuf + goff);
        *(short8*)&Ks[n * KPAD + dp * 8] = kk;
        *(short8*)&Vs[n * KPAD + dp * 8] = vv;
    }
    if (tid < 169) rpbs[tid] = rpb[head * 169 + tid];

    int p   = tid >> 2;
    int sub = tid & 3;
    int pi = ti0 + (p >> 3), pj = tj0 + (p & 7);
    int si = pi - 3; si = si < 0 ? 0 : (si > IMH - KSZ ? IMH - KSZ : si);
    int sj = pj - 3; sj = sj < 0 ? 0 : (sj > IMW - KSZ ? IMW - KSZ : sj);
    int bi = si - wi0, bj = sj - wj0;

    const float4* qp = (const float4*)(qbuf + (hbase + (size_t)(pi * IMW + pj)) * 32 + sub * 8);
    float4 q0 = qp[0], q1 = qp[1];
    float q[8] = {q0.x, q0.y, q0.z, q0.w, q1.x, q1.y, q1.z, q1.w};

    __syncthreads();

    float m = -1e30f, l = 0.f;
    float acc[8] = {};
    #pragma unroll
    for (int ki = 0; ki < KSZ; ki++) {
        int rbase = (bi + ki) * WIN + bj;
        const float* rb = &rpbs[(si + ki - pi + 6) * 13 + (sj - pj + 6)];
        #pragma unroll
        for (int kj = 0; kj < KSZ; kj++) {
            int n = rbase + kj;
            float kf[8];
            unpack8(&Ks[n * KPAD + sub * 8], kf);
            float d = q[0]*kf[0] + q[1]*kf[1] + q[2]*kf[2] + q[3]*kf[3]
                    + q[4]*kf[4] + q[5]*kf[5] + q[6]*kf[6] + q[7]*kf[7];
            d += __shfl_xor(d, 1);
            d += __shfl_xor(d, 2);
            float sc = d + rb[kj];
            float mn = fmaxf(m, sc);
            float co = __expf(m - mn);
            float pw = __expf(sc - mn);
            l = l * co + pw;
            float vf[8];
            unpack8(&Vs[n * KPAD + sub * 8], vf);
            #pragma unroll
            for (int e = 0; e < 8; e++) acc[e] = acc[e] * co + pw * vf[e];
            m = mn;
        }
    }
    float rl = 1.f / l;
    __hip_bfloat16* op = out + (size_t)(pi * IMW + pj) * DIM + head * HD + sub * 8;
    #pragma unroll
    for (int e = 0; e < 8; e++) op[e] = __float2bfloat16(acc[e] * rl);
}

extern "C" void kernel_launch(void* const* d_in, const int* in_sizes, int n_in,
                              void* d_out, int out_size, void* d_ws, size_t ws_size,
                              hipStream_t stream)
{
    const float* x      = (const float*)d_in[0];
    const float* qkv_w  = (const float*)d_in[1];
    const float* qkv_b  = (const float*)d_in[2];
    const float* proj_w = (const float*)d_in[3];
    const float* proj_b = (const float*)d_in[4];
    const float* rpb    = (const float*)d_in[5];
    const float* ln1_w  = (const float*)d_in[6];
    const float* ln1_b  = (const float*)d_in[7];
    const float* ln2_w  = (const float*)d_in[8];
    const float* ln2_b  = (const float*)d_in[9];
    const float* fc1_w  = (const float*)d_in[10];
    const float* fc1_b  = (const float*)d_in[11];
    const float* fc2_w  = (const float*)d_in[12];
    const float* fc2_b  = (const float*)d_in[13];
    const float* gamma1 = (const float*)d_in[14];
    const float* gamma2 = (const float*)d_in[15];
    const int*   quality= (const int*)d_in[16];
    float* out = (float*)d_out;

    char* ws = (char*)d_ws;
    float*          qbuf   = (float*)ws;                         // 12.58MB
    __hip_bfloat16* kbuf   = (__hip_bfloat16*)(ws + 12582912);   // 6.29MB
    __hip_bfloat16* vbuf   = (__hip_bfloat16*)(ws + 18874368);   // 6.29MB
    __hip_bfloat16* m1     = (__hip_bfloat16*)ws;                // aliases q/k/v after attention
    __hip_bfloat16* h      = (__hip_bfloat16*)(ws + 37748736);
    __hip_bfloat16* attn_b = (__hip_bfloat16*)(ws + 44040192);
    __hip_bfloat16* wq     = (__hip_bfloat16*)(ws + 50331648);
    __hip_bfloat16* wp     = (__hip_bfloat16*)(ws + 50552832);
    __hip_bfloat16* wf1    = (__hip_bfloat16*)(ws + 50626560);
    __hip_bfloat16* wf2    = (__hip_bfloat16*)(ws + 50921472);

    // 0. weights->bf16 + LN1 fused
    cvt_ln1<<<1728 + NPIX / 4, 256, 0, stream>>>(
        qkv_w, proj_w, fc1_w, fc2_w, wq, wp, wf1, wf2, x, ln1_w, ln1_b, h);
    // 1. QKV GEMM -> q fp32 planar (scaled) + k/v bf16 planar
    mfma_gemm<<<dim3(NPIX / GTM, 576 / GTN), 256, 0, stream>>>(
        h, wq, qkv_b, qbuf, nullptr, kbuf, vbuf, 576, DIM, 0);
    // 2. neighborhood attention -> attn_b (bf16)
    attn_kernel3<<<dim3(256, NHD), 256, 0, stream>>>(qbuf, kbuf, vbuf, rpb, attn_b);
    // 3. proj + residual + LN2 (fused): out = x + |g1|*(attn@wp^T+b), h = LN2(out)
    row_gemm<<<NPIX / 64, 256, 0, stream>>>(
        attn_b, wp, proj_b, out, h, x, gamma1, quality, ln2_w, ln2_b, DIM, 1);
    // 4. FC1 + GELU -> m1 (bf16)
    mfma_gemm<<<dim3(NPIX / GTM, HID / GTN), 256, 0, stream>>>(
        h, wf1, fc1_b, nullptr, m1, nullptr, nullptr, HID, DIM, 1);
    // 5. FC2 + residual: out += |g2|*(m1@wf2^T+b)
    row_gemm<<<NPIX / 64, 256, 0, stream>>>(
        m1, wf2, fc2_b, out, nullptr, out, gamma2, quality, nullptr, nullptr, HID, 0);
}

// Round 6
// 201.475 us; speedup vs baseline: 2.7478x; 1.0677x over previous
//
#include <hip/hip_runtime.h>
#include <hip/hip_bf16.h>
#include <math.h>

#define DIM 192
#define NHD 6
#define HD 32
#define KSZ 7
#define HID 768
#define IMH 128
#define IMW 128
#define NPIX (IMH*IMW)
#define WIN 14
#define KPAD 40

typedef __attribute__((ext_vector_type(8))) short short8;
typedef __attribute__((ext_vector_type(4))) float f32x4;

// ---------------- fused: weight fp32->bf16 (blocks 0..1727) + LN1 (blocks 1728..) ----------------
__global__ __launch_bounds__(256) void cvt_ln1(
    const float* __restrict__ qw, const float* __restrict__ pw,
    const float* __restrict__ f1, const float* __restrict__ f2,
    __hip_bfloat16* dq, __hip_bfloat16* dp, __hip_bfloat16* df1, __hip_bfloat16* df2,
    const float* __restrict__ x, const float* __restrict__ w, const float* __restrict__ b,
    __hip_bfloat16* __restrict__ hout)
{
    int blk = blockIdx.x, t = threadIdx.x;
    if (blk < 1728) {
        const float* s; __hip_bfloat16* d; int idx;
        if (blk < 432)       { s = qw; d = dq;  idx = blk * 256 + t; }
        else if (blk < 576)  { s = pw; d = dp;  idx = (blk - 432) * 256 + t; }
        else if (blk < 1152) { s = f1; d = df1; idx = (blk - 576) * 256 + t; }
        else                 { s = f2; d = df2; idx = (blk - 1152) * 256 + t; }
        d[idx] = __float2bfloat16(s[idx]);
        return;
    }
    int wid  = ((blk - 1728) * 256 + t) >> 6;
    int lane = t & 63;
    const float* xp = x + (size_t)wid * DIM;
    float v0 = xp[lane], v1 = xp[lane + 64], v2 = xp[lane + 128];
    float s = v0 + v1 + v2;
    #pragma unroll
    for (int off = 32; off > 0; off >>= 1) s += __shfl_down(s, off);
    float mu = __shfl(s, 0) * (1.0f / DIM);
    float d0 = v0 - mu, d1 = v1 - mu, d2 = v2 - mu;
    float q = d0*d0 + d1*d1 + d2*d2;
    #pragma unroll
    for (int off = 32; off > 0; off >>= 1) q += __shfl_down(q, off);
    float rstd = rsqrtf(__shfl(q, 0) * (1.0f / DIM) + 1e-5f);
    __hip_bfloat16* op = hout + (size_t)wid * DIM;
    op[lane]       = __float2bfloat16(d0 * rstd * w[lane]       + b[lane]);
    op[lane + 64]  = __float2bfloat16(d1 * rstd * w[lane + 64]  + b[lane + 64]);
    op[lane + 128] = __float2bfloat16(d2 * rstd * w[lane + 128] + b[lane + 128]);
}

__device__ __forceinline__ void gl_lds16(const void* g, void* l) {
    __builtin_amdgcn_global_load_lds(
        (const __attribute__((address_space(1))) void*)g,
        (__attribute__((address_space(3))) void*)l, 16, 0, 0);
}

// ---------------- MFMA bf16 GEMM: 128 x (32*FN) tile, BK=64, 4 waves (2x2) ----------------
// mode 0: qkv split -> q fp32 planar (scaled), k/v bf16 planar    mode 1: gelu -> bf16
#define GTM 128
#define GBK 64

template<int FN>
__global__ __launch_bounds__(256) void mfma_gemm(
    const __hip_bfloat16* A, const __hip_bfloat16* W, const float* bias,
    float* outf, __hip_bfloat16* outb, __hip_bfloat16* kb, __hip_bfloat16* vb,
    int N, int K, int mode)
{
    const int GTN = 32 * FN;
    __shared__ __hip_bfloat16 As[GTM * GBK];   // 16 KB
    __shared__ __hip_bfloat16 Bs[GTN * GBK];   // 12/16 KB
    int tid  = threadIdx.x;
    int wave = tid >> 6, lane = tid & 63;
    int m0 = blockIdx.x * GTM, n0 = blockIdx.y * GTN;
    int q = lane >> 4, col = lane & 15;
    int wm = (wave >> 1) * 64, wn = (wave & 1) * (FN * 16);

    f32x4 acc[4][FN] = {};

    for (int k0 = 0; k0 < K; k0 += GBK) {
        #pragma unroll
        for (int i = 0; i < 4; i++) {
            int c = i * 256 + tid;
            int r = c >> 3;
            int g = (c & 7) ^ (r & 7);
            gl_lds16(A + (size_t)(m0 + r) * K + k0 + g * 8,
                     (char*)As + (i * 256 + wave * 64) * 16);
        }
        #pragma unroll
        for (int i = 0; i < FN; i++) {
            int c = i * 256 + tid;
            int r = c >> 3;
            int g = (c & 7) ^ (r & 7);
            gl_lds16(W + (size_t)(n0 + r) * K + k0 + g * 8,
                     (char*)Bs + (i * 256 + wave * 64) * 16);
        }
        __syncthreads();

        #pragma unroll
        for (int kk = 0; kk < 2; kk++) {
            short8 af[4], bf[FN];
            #pragma unroll
            for (int mi = 0; mi < 4; mi++) {
                int r = wm + mi * 16 + col;
                int g = (kk * 4 + q) ^ (r & 7);
                af[mi] = *(const short8*)&As[r * GBK + g * 8];
            }
            #pragma unroll
            for (int ni = 0; ni < FN; ni++) {
                int r = wn + ni * 16 + col;
                int g = (kk * 4 + q) ^ (r & 7);
                bf[ni] = *(const short8*)&Bs[r * GBK + g * 8];
            }
            #pragma unroll
            for (int mi = 0; mi < 4; mi++)
                #pragma unroll
                for (int ni = 0; ni < FN; ni++)
                    acc[mi][ni] = __builtin_amdgcn_mfma_f32_16x16x32_bf16(
                        af[mi], bf[ni], acc[mi][ni], 0, 0, 0);
        }
        __syncthreads();
    }

    #pragma unroll
    for (int mi = 0; mi < 4; mi++) {
        #pragma unroll
        for (int r = 0; r < 4; r++) {
            int m = m0 + wm + mi * 16 + q * 4 + r;
            #pragma unroll
            for (int ni = 0; ni < FN; ni++) {
                int n = n0 + wn + ni * 16 + col;
                float v = acc[mi][ni][r] + bias[n];
                if (mode == 0) {
                    int h18 = n >> 5;
                    int sel = h18 / 6;
                    int head = h18 - sel * 6;
                    size_t idx = ((size_t)head * NPIX + m) * 32 + (n & 31);
                    if (sel == 0)      outf[idx] = v * 0.17677669529663687f;
                    else if (sel == 1) kb[idx] = __float2bfloat16(v);
                    else               vb[idx] = __float2bfloat16(v);
                } else {
                    // tanh-form GELU (max abs err ~3e-4)
                    float u = 0.7978845608f * (v + 0.044715f * v * v * v);
                    float t = 1.f - 2.f / (__expf(2.f * u) + 1.f);
                    v = 0.5f * v * (1.f + t);
                    outb[(size_t)m * N + n] = __float2bfloat16(v);
                }
            }
        }
    }
}

// ---------------- row GEMM: 32 rows x 192 cols per block (512 blocks) ----------------
// wave (mt,nh): M-tile mt (16 rows), N-half nh (96 cols = 6 frags)
// withln=1: fused LayerNorm of the full row -> hb bf16 (cross-wave LDS reduce)
#define RBK 64
__global__ __launch_bounds__(256) void row_gemm(
    const __hip_bfloat16* A, const __hip_bfloat16* W, const float* bias,
    float* outf, __hip_bfloat16* hb, const float* resid,
    const float* gamma, const int* quality,
    const float* lnw, const float* lnb, int K, int withln)
{
    __shared__ __hip_bfloat16 As[32 * RBK];     // 4 KB
    __shared__ __hip_bfloat16 Bs[192 * RBK];    // 24 KB
    __shared__ float red[2][32][2];             // [nh][row][sum,sq]
    int tid = threadIdx.x;
    int wave = tid >> 6, lane = tid & 63;
    int q = lane >> 4, col = lane & 15;
    int mt = wave & 1, nh = wave >> 1;
    int m0 = blockIdx.x * 32;

    f32x4 acc[6] = {};
    for (int k0 = 0; k0 < K; k0 += RBK) {
        {   // A: 256 chunks, 1/thread
            int r = tid >> 3;
            int g = (tid & 7) ^ (r & 7);
            gl_lds16(A + (size_t)(m0 + r) * K + k0 + g * 8,
                     (char*)As + (wave * 64) * 16);
        }
        #pragma unroll
        for (int i = 0; i < 6; i++) {
            int c = i * 256 + tid;
            int r = c >> 3;
            int g = (c & 7) ^ (r & 7);
            gl_lds16(W + (size_t)r * K + k0 + g * 8,
                     (char*)Bs + (i * 256 + wave * 64) * 16);
        }
        __syncthreads();
        #pragma unroll
        for (int kk = 0; kk < 2; kk++) {
            int rA = mt * 16 + col;
            short8 af = *(const short8*)&As[rA * RBK + (((kk * 4 + q) ^ (rA & 7)) * 8)];
            #pragma unroll
            for (int f = 0; f < 6; f++) {
                int rB = nh * 96 + f * 16 + col;
                short8 bf = *(const short8*)&Bs[rB * RBK + (((kk * 4 + q) ^ (rB & 7)) * 8)];
                acc[f] = __builtin_amdgcn_mfma_f32_16x16x32_bf16(af, bf, acc[f], 0, 0, 0);
            }
        }
        __syncthreads();
    }

    int s = quality[0] - 1;
    float v[6][4];
    #pragma unroll
    for (int f = 0; f < 6; f++) {
        int n = nh * 96 + f * 16 + col;
        float bi = bias[n];
        float g = fabsf(gamma[s * DIM + n]);
        #pragma unroll
        for (int r = 0; r < 4; r++) {
            int m = m0 + mt * 16 + q * 4 + r;
            v[f][r] = resid[(size_t)m * DIM + n] + g * (acc[f][r] + bi);
            outf[(size_t)m * DIM + n] = v[f][r];
        }
    }
    if (withln) {
        float sm[4] = {}, sq[4] = {};
        #pragma unroll
        for (int f = 0; f < 6; f++)
            #pragma unroll
            for (int r = 0; r < 4; r++) { sm[r] += v[f][r]; sq[r] += v[f][r] * v[f][r]; }
        #pragma unroll
        for (int off = 1; off <= 8; off <<= 1) {
            #pragma unroll
            for (int r = 0; r < 4; r++) {
                sm[r] += __shfl_xor(sm[r], off);
                sq[r] += __shfl_xor(sq[r], off);
            }
        }
        if (col == 0) {
            #pragma unroll
            for (int r = 0; r < 4; r++) {
                red[nh][mt * 16 + q * 4 + r][0] = sm[r];
                red[nh][mt * 16 + q * 4 + r][1] = sq[r];
            }
        }
        __syncthreads();
        float mu[4], rstd[4];
        #pragma unroll
        for (int r = 0; r < 4; r++) {
            int row = mt * 16 + q * 4 + r;
            float tm = red[0][row][0] + red[1][row][0];
            float tq = red[0][row][1] + red[1][row][1];
            mu[r] = tm * (1.0f / DIM);
            float var = tq * (1.0f / DIM) - mu[r] * mu[r];
            rstd[r] = rsqrtf(var + 1e-5f);
        }
        #pragma unroll
        for (int f = 0; f < 6; f++) {
            int n = nh * 96 + f * 16 + col;
            float lw = lnw[n], lb = lnb[n];
            #pragma unroll
            for (int r = 0; r < 4; r++) {
                int m = m0 + mt * 16 + q * 4 + r;
                hb[(size_t)m * DIM + n] =
                    __float2bfloat16((v[f][r] - mu[r]) * rstd[r] * lw + lb);
            }
        }
    }
}

// ---------------- Neighborhood attention: bf16 K/V, row-batched online softmax ----------------
__device__ __forceinline__ void unpack8(const __hip_bfloat16* ptr, float* f) {
    short8 s8 = *(const short8*)ptr;
    union { short8 v; unsigned u[4]; } c; c.v = s8;
    #pragma unroll
    for (int w = 0; w < 4; w++) {
        f[2*w]   = __uint_as_float(c.u[w] << 16);
        f[2*w+1] = __uint_as_float(c.u[w] & 0xffff0000u);
    }
}

__global__ __launch_bounds__(256, 4) void attn_kernel3(
    const float* __restrict__ qbuf, const __hip_bfloat16* __restrict__ kbuf,
    const __hip_bfloat16* __restrict__ vbuf, const float* __restrict__ rpb,
    __hip_bfloat16* __restrict__ out)
{
    __shared__ __hip_bfloat16 Ks[WIN * WIN * KPAD];
    __shared__ __hip_bfloat16 Vs[WIN * WIN * KPAD];
    __shared__ float rpbs[169];

    int head = blockIdx.y;
    int tile = blockIdx.x;
    int ti0 = (tile >> 4) * 8;
    int tj0 = (tile & 15) * 8;
    int wi0 = ti0 - 3; wi0 = wi0 < 0 ? 0 : (wi0 > IMH - WIN ? IMH - WIN : wi0);
    int wj0 = tj0 - 3; wj0 = wj0 < 0 ? 0 : (wj0 > IMW - WIN ? IMW - WIN : wj0);

    int tid = threadIdx.x;
    const size_t hbase = (size_t)head * NPIX;

    for (int c = tid; c < 784; c += 256) {
        int i = c / 56, part = c - i * 56;
        int n = i * WIN + (part >> 2);
        int dp = part & 3;
        size_t goff = (hbase + (size_t)(wi0 + i) * IMW + wj0) * 32 + part * 8;
        short8 kk = *(const short8*)(kbuf + goff);
        short8 vv = *(const short8*)(vbuf + goff);
        *(short8*)&Ks[n * KPAD + dp * 8] = kk;
        *(short8*)&Vs[n * KPAD + dp * 8] = vv;
    }
    if (tid < 169) rpbs[tid] = rpb[head * 169 + tid];

    int p   = tid >> 2;
    int sub = tid & 3;
    int pi = ti0 + (p >> 3), pj = tj0 + (p & 7);
    int si = pi - 3; si = si < 0 ? 0 : (si > IMH - KSZ ? IMH - KSZ : si);
    int sj = pj - 3; sj = sj < 0 ? 0 : (sj > IMW - KSZ ? IMW - KSZ : sj);
    int bi = si - wi0, bj = sj - wj0;

    const float4* qp = (const float4*)(qbuf + (hbase + (size_t)(pi * IMW + pj)) * 32 + sub * 8);
    float4 q0 = qp[0], q1 = qp[1];
    float q[8] = {q0.x, q0.y, q0.z, q0.w, q1.x, q1.y, q1.z, q1.w};

    __syncthreads();

    float m = -1e30f, l = 0.f;
    float acc[8] = {};
    #pragma unroll
    for (int ki = 0; ki < KSZ; ki++) {
        int rbase = (bi + ki) * WIN + bj;
        const float* rb = &rpbs[(si + ki - pi + 6) * 13 + (sj - pj + 6)];
        float s7[KSZ];
        #pragma unroll
        for (int kj = 0; kj < KSZ; kj++) {
            float kf[8];
            unpack8(&Ks[(rbase + kj) * KPAD + sub * 8], kf);
            float d = q[0]*kf[0] + q[1]*kf[1] + q[2]*kf[2] + q[3]*kf[3]
                    + q[4]*kf[4] + q[5]*kf[5] + q[6]*kf[6] + q[7]*kf[7];
            d += __shfl_xor(d, 1);
            d += __shfl_xor(d, 2);
            s7[kj] = d + rb[kj];
        }
        float rmax = s7[0];
        #pragma unroll
        for (int kj = 1; kj < KSZ; kj++) rmax = fmaxf(rmax, s7[kj]);
        float mn = fmaxf(m, rmax);
        float co = __expf(m - mn);
        l *= co;
        #pragma unroll
        for (int e = 0; e < 8; e++) acc[e] *= co;
        #pragma unroll
        for (int kj = 0; kj < KSZ; kj++) {
            float pw = __expf(s7[kj] - mn);
            l += pw;
            float vf[8];
            unpack8(&Vs[(rbase + kj) * KPAD + sub * 8], vf);
            #pragma unroll
            for (int e = 0; e < 8; e++) acc[e] += pw * vf[e];
        }
        m = mn;
    }
    float rl = 1.f / l;
    __hip_bfloat16* op = out + (size_t)(pi * IMW + pj) * DIM + head * HD + sub * 8;
    #pragma unroll
    for (int e = 0; e < 8; e++) op[e] = __float2bfloat16(acc[e] * rl);
}

extern "C" void kernel_launch(void* const* d_in, const int* in_sizes, int n_in,
                              void* d_out, int out_size, void* d_ws, size_t ws_size,
                              hipStream_t stream)
{
    const float* x      = (const float*)d_in[0];
    const float* qkv_w  = (const float*)d_in[1];
    const float* qkv_b  = (const float*)d_in[2];
    const float* proj_w = (const float*)d_in[3];
    const float* proj_b = (const float*)d_in[4];
    const float* rpb    = (const float*)d_in[5];
    const float* ln1_w  = (const float*)d_in[6];
    const float* ln1_b  = (const float*)d_in[7];
    const float* ln2_w  = (const float*)d_in[8];
    const float* ln2_b  = (const float*)d_in[9];
    const float* fc1_w  = (const float*)d_in[10];
    const float* fc1_b  = (const float*)d_in[11];
    const float* fc2_w  = (const float*)d_in[12];
    const float* fc2_b  = (const float*)d_in[13];
    const float* gamma1 = (const float*)d_in[14];
    const float* gamma2 = (const float*)d_in[15];
    const int*   quality= (const int*)d_in[16];
    float* out = (float*)d_out;

    char* ws = (char*)d_ws;
    float*          qbuf   = (float*)ws;                         // 12.58MB
    __hip_bfloat16* kbuf   = (__hip_bfloat16*)(ws + 12582912);   // 6.29MB
    __hip_bfloat16* vbuf   = (__hip_bfloat16*)(ws + 18874368);   // 6.29MB
    __hip_bfloat16* m1     = (__hip_bfloat16*)ws;                // aliases q/k/v after attention
    __hip_bfloat16* h      = (__hip_bfloat16*)(ws + 37748736);
    __hip_bfloat16* attn_b = (__hip_bfloat16*)(ws + 44040192);
    __hip_bfloat16* wq     = (__hip_bfloat16*)(ws + 50331648);
    __hip_bfloat16* wp     = (__hip_bfloat16*)(ws + 50552832);
    __hip_bfloat16* wf1    = (__hip_bfloat16*)(ws + 50626560);
    __hip_bfloat16* wf2    = (__hip_bfloat16*)(ws + 50921472);

    // 0. weights->bf16 + LN1 fused
    cvt_ln1<<<1728 + NPIX / 4, 256, 0, stream>>>(
        qkv_w, proj_w, fc1_w, fc2_w, wq, wp, wf1, wf2, x, ln1_w, ln1_b, h);
    // 1. QKV GEMM (128x96 tiles) -> q fp32 planar (scaled) + k/v bf16 planar
    mfma_gemm<3><<<dim3(NPIX / GTM, 6), 256, 0, stream>>>(
        h, wq, qkv_b, qbuf, nullptr, kbuf, vbuf, 576, DIM, 0);
    // 2. neighborhood attention -> attn_b (bf16)
    attn_kernel3<<<dim3(256, NHD), 256, 0, stream>>>(qbuf, kbuf, vbuf, rpb, attn_b);
    // 3. proj + residual + LN2 (fused): out = x + |g1|*(attn@wp^T+b), h = LN2(out)
    row_gemm<<<NPIX / 32, 256, 0, stream>>>(
        attn_b, wp, proj_b, out, h, x, gamma1, quality, ln2_w, ln2_b, DIM, 1);
    // 4. FC1 + GELU (128x128 tiles) -> m1 (bf16)
    mfma_gemm<4><<<dim3(NPIX / GTM, 6), 256, 0, stream>>>(
        h, wf1, fc1_b, nullptr, m1, nullptr, nullptr, HID, DIM, 1);
    // 5. FC2 + residual: out += |g2|*(m1@wf2^T+b)
    row_gemm<<<NPIX / 32, 256, 0, stream>>>(
        m1, wf2, fc2_b, out, nullptr, out, gamma2, quality, nullptr, nullptr, HID, 0);
}

// Round 7
// 181.854 us; speedup vs baseline: 3.0443x; 1.1079x over previous
//
#include <hip/hip_runtime.h>
#include <hip/hip_bf16.h>
#include <math.h>

#define DIM 192
#define NHD 6
#define HD 32
#define KSZ 7
#define HID 768
#define IMH 128
#define IMW 128
#define NPIX (IMH*IMW)
#define WIN 14
#define KPAD 40

typedef __attribute__((ext_vector_type(8))) short short8;
typedef __attribute__((ext_vector_type(4))) float f32x4;

// ---------------- fused: weight fp32->bf16 (blocks 0..1727) + LN1 (blocks 1728..) ----------------
__global__ __launch_bounds__(256) void cvt_ln1(
    const float* __restrict__ qw, const float* __restrict__ pw,
    const float* __restrict__ f1, const float* __restrict__ f2,
    __hip_bfloat16* dq, __hip_bfloat16* dp, __hip_bfloat16* df1, __hip_bfloat16* df2,
    const float* __restrict__ x, const float* __restrict__ w, const float* __restrict__ b,
    __hip_bfloat16* __restrict__ hout)
{
    int blk = blockIdx.x, t = threadIdx.x;
    if (blk < 1728) {
        const float* s; __hip_bfloat16* d; int idx;
        if (blk < 432)       { s = qw; d = dq;  idx = blk * 256 + t; }
        else if (blk < 576)  { s = pw; d = dp;  idx = (blk - 432) * 256 + t; }
        else if (blk < 1152) { s = f1; d = df1; idx = (blk - 576) * 256 + t; }
        else                 { s = f2; d = df2; idx = (blk - 1152) * 256 + t; }
        d[idx] = __float2bfloat16(s[idx]);
        return;
    }
    int wid  = ((blk - 1728) * 256 + t) >> 6;
    int lane = t & 63;
    const float* xp = x + (size_t)wid * DIM;
    float v0 = xp[lane], v1 = xp[lane + 64], v2 = xp[lane + 128];
    float s = v0 + v1 + v2;
    #pragma unroll
    for (int off = 32; off > 0; off >>= 1) s += __shfl_down(s, off);
    float mu = __shfl(s, 0) * (1.0f / DIM);
    float d0 = v0 - mu, d1 = v1 - mu, d2 = v2 - mu;
    float q = d0*d0 + d1*d1 + d2*d2;
    #pragma unroll
    for (int off = 32; off > 0; off >>= 1) q += __shfl_down(q, off);
    float rstd = rsqrtf(__shfl(q, 0) * (1.0f / DIM) + 1e-5f);
    __hip_bfloat16* op = hout + (size_t)wid * DIM;
    op[lane]       = __float2bfloat16(d0 * rstd * w[lane]       + b[lane]);
    op[lane + 64]  = __float2bfloat16(d1 * rstd * w[lane + 64]  + b[lane + 64]);
    op[lane + 128] = __float2bfloat16(d2 * rstd * w[lane + 128] + b[lane + 128]);
}

__device__ __forceinline__ void gl_lds16(const void* g, void* l) {
    __builtin_amdgcn_global_load_lds(
        (const __attribute__((address_space(1))) void*)g,
        (__attribute__((address_space(3))) void*)l, 16, 0, 0);
}

// ---------------- single-K-shot GEMM: tile 128x64, K=192 staged whole, ONE barrier ----------------
// LDS rows are 384B (192 bf16); in-row XOR swizzle kc^=(r&7) keeps b128 reads 2-way (free).
// mode 0: qkv split -> q fp32 planar (scaled) + k/v bf16 planar   mode 1: gelu -> bf16
template<int mode>
__global__ __launch_bounds__(256) void gemm_k192(
    const __hip_bfloat16* __restrict__ A, const __hip_bfloat16* __restrict__ W,
    const float* __restrict__ bias,
    float* outf, __hip_bfloat16* outb, __hip_bfloat16* kb, __hip_bfloat16* vb, int N)
{
    __shared__ __hip_bfloat16 As[128 * 192];   // 48 KB
    __shared__ __hip_bfloat16 Bs[64 * 192];    // 24 KB
    int tid = threadIdx.x;
    int wave = tid >> 6, lane = tid & 63;
    int m0 = blockIdx.x * 128, n0 = blockIdx.y * 64;
    int q = lane >> 4, col = lane & 15;
    int wm = (wave >> 1) * 64, wn = (wave & 1) * 32;

    const __hip_bfloat16* Ab = A + (size_t)m0 * 192;
    #pragma unroll
    for (int i = 0; i < 12; i++) {
        int c = i * 256 + tid;
        int r = c / 24, kc = c - r * 24;
        int g = kc ^ (r & 7);
        gl_lds16(Ab + r * 192 + g * 8, (char*)As + (i * 256 + wave * 64) * 16);
    }
    const __hip_bfloat16* Wb = W + (size_t)n0 * 192;
    #pragma unroll
    for (int i = 0; i < 6; i++) {
        int c = i * 256 + tid;
        int r = c / 24, kc = c - r * 24;
        int g = kc ^ (r & 7);
        gl_lds16(Wb + r * 192 + g * 8, (char*)Bs + (i * 256 + wave * 64) * 16);
    }
    __syncthreads();

    f32x4 acc[4][2] = {};
    #pragma unroll
    for (int ks = 0; ks < 6; ks++) {
        short8 af[4], bf[2];
        #pragma unroll
        for (int mi = 0; mi < 4; mi++) {
            int r = wm + mi * 16 + col;
            af[mi] = *(const short8*)&As[r * 192 + (((ks * 4 + q) ^ (r & 7)) * 8)];
        }
        #pragma unroll
        for (int ni = 0; ni < 2; ni++) {
            int r = wn + ni * 16 + col;
            bf[ni] = *(const short8*)&Bs[r * 192 + (((ks * 4 + q) ^ (r & 7)) * 8)];
        }
        #pragma unroll
        for (int mi = 0; mi < 4; mi++)
            #pragma unroll
            for (int ni = 0; ni < 2; ni++)
                acc[mi][ni] = __builtin_amdgcn_mfma_f32_16x16x32_bf16(
                    af[mi], bf[ni], acc[mi][ni], 0, 0, 0);
    }

    #pragma unroll
    for (int mi = 0; mi < 4; mi++) {
        #pragma unroll
        for (int r = 0; r < 4; r++) {
            int m = m0 + wm + mi * 16 + q * 4 + r;
            #pragma unroll
            for (int ni = 0; ni < 2; ni++) {
                int n = n0 + wn + ni * 16 + col;
                float v = acc[mi][ni][r] + bias[n];
                if (mode == 0) {
                    int h18 = n >> 5;
                    int sel = h18 / 6;
                    int head = h18 - sel * 6;
                    size_t idx = ((size_t)head * NPIX + m) * 32 + (n & 31);
                    if (sel == 0)      outf[idx] = v * 0.17677669529663687f;
                    else if (sel == 1) kb[idx] = __float2bfloat16(v);
                    else               vb[idx] = __float2bfloat16(v);
                } else {
                    float u = 0.7978845608f * (v + 0.044715f * v * v * v);
                    float t = 1.f - 2.f / (__expf(2.f * u) + 1.f);
                    v = 0.5f * v * (1.f + t);
                    outb[(size_t)m * N + n] = __float2bfloat16(v);
                }
            }
        }
    }
}

// ---------------- proj + residual + |g1| + fused LN2: 64 rows x 192 cols, one barrier ----------------
__global__ __launch_bounds__(256) void proj_ln(
    const __hip_bfloat16* __restrict__ A, const __hip_bfloat16* __restrict__ W,
    const float* __restrict__ bias,
    float* outf, __hip_bfloat16* hb, const float* __restrict__ resid,
    const float* __restrict__ gamma, const int* __restrict__ quality,
    const float* __restrict__ lnw, const float* __restrict__ lnb)
{
    __shared__ __hip_bfloat16 As[64 * 192];    // 24 KB
    __shared__ __hip_bfloat16 Bs[192 * 192];   // 72 KB
    int tid = threadIdx.x;
    int wave = tid >> 6, lane = tid & 63;
    int q = lane >> 4, col = lane & 15;
    int m0 = blockIdx.x * 64;

    const __hip_bfloat16* Ab = A + (size_t)m0 * 192;
    #pragma unroll
    for (int i = 0; i < 6; i++) {
        int c = i * 256 + tid;
        int r = c / 24, kc = c - r * 24;
        int g = kc ^ (r & 7);
        gl_lds16(Ab + r * 192 + g * 8, (char*)As + (i * 256 + wave * 64) * 16);
    }
    #pragma unroll
    for (int i = 0; i < 18; i++) {
        int c = i * 256 + tid;
        int r = c / 24, kc = c - r * 24;
        int g = kc ^ (r & 7);
        gl_lds16(W + r * 192 + g * 8, (char*)Bs + (i * 256 + wave * 64) * 16);
    }
    __syncthreads();

    f32x4 acc[12] = {};
    #pragma unroll
    for (int ks = 0; ks < 6; ks++) {
        int rA = wave * 16 + col;
        short8 af = *(const short8*)&As[rA * 192 + (((ks * 4 + q) ^ (rA & 7)) * 8)];
        #pragma unroll
        for (int f = 0; f < 12; f++) {
            int rB = f * 16 + col;
            short8 bf = *(const short8*)&Bs[rB * 192 + (((ks * 4 + q) ^ (rB & 7)) * 8)];
            acc[f] = __builtin_amdgcn_mfma_f32_16x16x32_bf16(af, bf, acc[f], 0, 0, 0);
        }
    }

    int s = quality[0] - 1;
    float v[12][4];
    #pragma unroll
    for (int f = 0; f < 12; f++) {
        int n = f * 16 + col;
        float bi = bias[n];
        float g = fabsf(gamma[s * DIM + n]);
        #pragma unroll
        for (int r = 0; r < 4; r++) {
            int m = m0 + wave * 16 + q * 4 + r;
            v[f][r] = resid[(size_t)m * DIM + n] + g * (acc[f][r] + bi);
            outf[(size_t)m * DIM + n] = v[f][r];
        }
    }
    // wave-local LN2 (full 192-col row lives in this wave's 16-lane col group)
    float sm[4] = {}, sq[4] = {};
    #pragma unroll
    for (int f = 0; f < 12; f++)
        #pragma unroll
        for (int r = 0; r < 4; r++) { sm[r] += v[f][r]; sq[r] += v[f][r] * v[f][r]; }
    #pragma unroll
    for (int off = 1; off <= 8; off <<= 1) {
        #pragma unroll
        for (int r = 0; r < 4; r++) {
            sm[r] += __shfl_xor(sm[r], off);
            sq[r] += __shfl_xor(sq[r], off);
        }
    }
    float mu[4], rstd[4];
    #pragma unroll
    for (int r = 0; r < 4; r++) {
        mu[r] = sm[r] * (1.0f / DIM);
        float var = sq[r] * (1.0f / DIM) - mu[r] * mu[r];
        rstd[r] = rsqrtf(var + 1e-5f);
    }
    #pragma unroll
    for (int f = 0; f < 12; f++) {
        int n = f * 16 + col;
        float lw = lnw[n], lb = lnb[n];
        #pragma unroll
        for (int r = 0; r < 4; r++) {
            int m = m0 + wave * 16 + q * 4 + r;
            hb[(size_t)m * DIM + n] = __float2bfloat16((v[f][r] - mu[r]) * rstd[r] * lw + lb);
        }
    }
}

// ---------------- FC2: tile 64x64, BK=192 (4 iters), + resid + |g2| ----------------
__global__ __launch_bounds__(256) void fc2_gemm(
    const __hip_bfloat16* __restrict__ A, const __hip_bfloat16* __restrict__ W,
    const float* __restrict__ bias,
    float* outf, const float* __restrict__ resid,
    const float* __restrict__ gamma, const int* __restrict__ quality)
{
    __shared__ __hip_bfloat16 As[64 * 192];   // 24 KB
    __shared__ __hip_bfloat16 Bs[64 * 192];   // 24 KB
    int tid = threadIdx.x;
    int wave = tid >> 6, lane = tid & 63;
    int q = lane >> 4, col = lane & 15;
    int m0 = blockIdx.x * 64, n0 = blockIdx.y * 64;
    int wm = (wave >> 1) * 32, wn = (wave & 1) * 32;

    f32x4 acc[2][2] = {};
    for (int k0 = 0; k0 < HID; k0 += 192) {
        #pragma unroll
        for (int i = 0; i < 6; i++) {
            int c = i * 256 + tid;
            int r = c / 24, kc = c - r * 24;
            int g = kc ^ (r & 7);
            gl_lds16(A + (size_t)(m0 + r) * HID + k0 + g * 8,
                     (char*)As + (i * 256 + wave * 64) * 16);
        }
        #pragma unroll
        for (int i = 0; i < 6; i++) {
            int c = i * 256 + tid;
            int r = c / 24, kc = c - r * 24;
            int g = kc ^ (r & 7);
            gl_lds16(W + (size_t)(n0 + r) * HID + k0 + g * 8,
                     (char*)Bs + (i * 256 + wave * 64) * 16);
        }
        __syncthreads();
        #pragma unroll
        for (int ks = 0; ks < 6; ks++) {
            short8 af[2], bf[2];
            #pragma unroll
            for (int mi = 0; mi < 2; mi++) {
                int r = wm + mi * 16 + col;
                af[mi] = *(const short8*)&As[r * 192 + (((ks * 4 + q) ^ (r & 7)) * 8)];
            }
            #pragma unroll
            for (int ni = 0; ni < 2; ni++) {
                int r = wn + ni * 16 + col;
                bf[ni] = *(const short8*)&Bs[r * 192 + (((ks * 4 + q) ^ (r & 7)) * 8)];
            }
            #pragma unroll
            for (int mi = 0; mi < 2; mi++)
                #pragma unroll
                for (int ni = 0; ni < 2; ni++)
                    acc[mi][ni] = __builtin_amdgcn_mfma_f32_16x16x32_bf16(
                        af[mi], bf[ni], acc[mi][ni], 0, 0, 0);
        }
        __syncthreads();
    }

    int s = quality[0] - 1;
    #pragma unroll
    for (int mi = 0; mi < 2; mi++) {
        #pragma unroll
        for (int r = 0; r < 4; r++) {
            int m = m0 + wm + mi * 16 + q * 4 + r;
            #pragma unroll
            for (int ni = 0; ni < 2; ni++) {
                int n = n0 + wn + ni * 16 + col;
                float g = fabsf(gamma[s * DIM + n]);
                outf[(size_t)m * DIM + n] =
                    resid[(size_t)m * DIM + n] + g * (acc[mi][ni][r] + bias[n]);
            }
        }
    }
}

// ---------------- Neighborhood attention: bf16 K/V, row-batched online softmax ----------------
__device__ __forceinline__ void unpack8(const __hip_bfloat16* ptr, float* f) {
    short8 s8 = *(const short8*)ptr;
    union { short8 v; unsigned u[4]; } c; c.v = s8;
    #pragma unroll
    for (int w = 0; w < 4; w++) {
        f[2*w]   = __uint_as_float(c.u[w] << 16);
        f[2*w+1] = __uint_as_float(c.u[w] & 0xffff0000u);
    }
}

__global__ __launch_bounds__(256, 4) void attn_kernel3(
    const float* __restrict__ qbuf, const __hip_bfloat16* __restrict__ kbuf,
    const __hip_bfloat16* __restrict__ vbuf, const float* __restrict__ rpb,
    __hip_bfloat16* __restrict__ out)
{
    __shared__ __hip_bfloat16 Ks[WIN * WIN * KPAD];
    __shared__ __hip_bfloat16 Vs[WIN * WIN * KPAD];
    __shared__ float rpbs[169];

    int head = blockIdx.y;
    int tile = blockIdx.x;
    int ti0 = (tile >> 4) * 8;
    int tj0 = (tile & 15) * 8;
    int wi0 = ti0 - 3; wi0 = wi0 < 0 ? 0 : (wi0 > IMH - WIN ? IMH - WIN : wi0);
    int wj0 = tj0 - 3; wj0 = wj0 < 0 ? 0 : (wj0 > IMW - WIN ? IMW - WIN : wj0);

    int tid = threadIdx.x;
    const size_t hbase = (size_t)head * NPIX;

    for (int c = tid; c < 784; c += 256) {
        int i = c / 56, part = c - i * 56;
        int n = i * WIN + (part >> 2);
        int dp = part & 3;
        size_t goff = (hbase + (size_t)(wi0 + i) * IMW + wj0) * 32 + part * 8;
        short8 kk = *(const short8*)(kbuf + goff);
        short8 vv = *(const short8*)(vbuf + goff);
        *(short8*)&Ks[n * KPAD + dp * 8] = kk;
        *(short8*)&Vs[n * KPAD + dp * 8] = vv;
    }
    if (tid < 169) rpbs[tid] = rpb[head * 169 + tid];

    int p   = tid >> 2;
    int sub = tid & 3;
    int pi = ti0 + (p >> 3), pj = tj0 + (p & 7);
    int si = pi - 3; si = si < 0 ? 0 : (si > IMH - KSZ ? IMH - KSZ : si);
    int sj = pj - 3; sj = sj < 0 ? 0 : (sj > IMW - KSZ ? IMW - KSZ : sj);
    int bi = si - wi0, bj = sj - wj0;

    const float4* qp = (const float4*)(qbuf + (hbase + (size_t)(pi * IMW + pj)) * 32 + sub * 8);
    float4 q0 = qp[0], q1 = qp[1];
    float q[8] = {q0.x, q0.y, q0.z, q0.w, q1.x, q1.y, q1.z, q1.w};

    __syncthreads();

    float m = -1e30f, l = 0.f;
    float acc[8] = {};
    #pragma unroll
    for (int ki = 0; ki < KSZ; ki++) {
        int rbase = (bi + ki) * WIN + bj;
        const float* rb = &rpbs[(si + ki - pi + 6) * 13 + (sj - pj + 6)];
        float s7[KSZ];
        #pragma unroll
        for (int kj = 0; kj < KSZ; kj++) {
            float kf[8];
            unpack8(&Ks[(rbase + kj) * KPAD + sub * 8], kf);
            float d = q[0]*kf[0] + q[1]*kf[1] + q[2]*kf[2] + q[3]*kf[3]
                    + q[4]*kf[4] + q[5]*kf[5] + q[6]*kf[6] + q[7]*kf[7];
            d += __shfl_xor(d, 1);
            d += __shfl_xor(d, 2);
            s7[kj] = d + rb[kj];
        }
        float rmax = s7[0];
        #pragma unroll
        for (int kj = 1; kj < KSZ; kj++) rmax = fmaxf(rmax, s7[kj]);
        float mn = fmaxf(m, rmax);
        float co = __expf(m - mn);
        l *= co;
        #pragma unroll
        for (int e = 0; e < 8; e++) acc[e] *= co;
        #pragma unroll
        for (int kj = 0; kj < KSZ; kj++) {
            float pw = __expf(s7[kj] - mn);
            l += pw;
            float vf[8];
            unpack8(&Vs[(rbase + kj) * KPAD + sub * 8], vf);
            #pragma unroll
            for (int e = 0; e < 8; e++) acc[e] += pw * vf[e];
        }
        m = mn;
    }
    float rl = 1.f / l;
    __hip_bfloat16* op = out + (size_t)(pi * IMW + pj) * DIM + head * HD + sub * 8;
    #pragma unroll
    for (int e = 0; e < 8; e++) op[e] = __float2bfloat16(acc[e] * rl);
}

extern "C" void kernel_launch(void* const* d_in, const int* in_sizes, int n_in,
                              void* d_out, int out_size, void* d_ws, size_t ws_size,
                              hipStream_t stream)
{
    const float* x      = (const float*)d_in[0];
    const float* qkv_w  = (const float*)d_in[1];
    const float* qkv_b  = (const float*)d_in[2];
    const float* proj_w = (const float*)d_in[3];
    const float* proj_b = (const float*)d_in[4];
    const float* rpb    = (const float*)d_in[5];
    const float* ln1_w  = (const float*)d_in[6];
    const float* ln1_b  = (const float*)d_in[7];
    const float* ln2_w  = (const float*)d_in[8];
    const float* ln2_b  = (const float*)d_in[9];
    const float* fc1_w  = (const float*)d_in[10];
    const float* fc1_b  = (const float*)d_in[11];
    const float* fc2_w  = (const float*)d_in[12];
    const float* fc2_b  = (const float*)d_in[13];
    const float* gamma1 = (const float*)d_in[14];
    const float* gamma2 = (const float*)d_in[15];
    const int*   quality= (const int*)d_in[16];
    float* out = (float*)d_out;

    char* ws = (char*)d_ws;
    float*          qbuf   = (float*)ws;                         // 12.58MB
    __hip_bfloat16* kbuf   = (__hip_bfloat16*)(ws + 12582912);   // 6.29MB
    __hip_bfloat16* vbuf   = (__hip_bfloat16*)(ws + 18874368);   // 6.29MB
    __hip_bfloat16* m1     = (__hip_bfloat16*)ws;                // aliases q/k/v after attention
    __hip_bfloat16* h      = (__hip_bfloat16*)(ws + 37748736);
    __hip_bfloat16* attn_b = (__hip_bfloat16*)(ws + 44040192);
    __hip_bfloat16* wq     = (__hip_bfloat16*)(ws + 50331648);
    __hip_bfloat16* wp     = (__hip_bfloat16*)(ws + 50552832);
    __hip_bfloat16* wf1    = (__hip_bfloat16*)(ws + 50626560);
    __hip_bfloat16* wf2    = (__hip_bfloat16*)(ws + 50921472);

    // 0. weights->bf16 + LN1 fused
    cvt_ln1<<<1728 + NPIX / 4, 256, 0, stream>>>(
        qkv_w, proj_w, fc1_w, fc2_w, wq, wp, wf1, wf2, x, ln1_w, ln1_b, h);
    // 1. QKV GEMM (single-K-shot 128x64) -> q fp32 planar (scaled) + k/v bf16 planar
    gemm_k192<0><<<dim3(NPIX / 128, 9), 256, 0, stream>>>(
        h, wq, qkv_b, qbuf, nullptr, kbuf, vbuf, 576);
    // 2. neighborhood attention -> attn_b (bf16)
    attn_kernel3<<<dim3(256, NHD), 256, 0, stream>>>(qbuf, kbuf, vbuf, rpb, attn_b);
    // 3. proj + residual + LN2 (fused, single-shot): out = x + |g1|*(attn@wp^T+b), h = LN2(out)
    proj_ln<<<NPIX / 64, 256, 0, stream>>>(
        attn_b, wp, proj_b, out, h, x, gamma1, quality, ln2_w, ln2_b);
    // 4. FC1 + GELU (single-K-shot 128x64) -> m1 (bf16)
    gemm_k192<1><<<dim3(NPIX / 128, 12), 256, 0, stream>>>(
        h, wf1, fc1_b, nullptr, m1, nullptr, nullptr, HID);
    // 5. FC2 + residual (64x64, BK=192): out += |g2|*(m1@wf2^T+b)
    fc2_gemm<<<dim3(NPIX / 64, 3), 256, 0, stream>>>(
        m1, wf2, fc2_b, out, out, gamma2, quality);
}